// Round 8
// baseline (7713.946 us; speedup 1.0000x reference)
//
#include <hip/hip_runtime.h>

#define NN 20000      // nodes
#define NE 160000     // edges per edge set
#define NL 20         // EGNN layer calls (4*DEPTH)

typedef float f32x4 __attribute__((ext_vector_type(4)));
typedef float f32x2 __attribute__((ext_vector_type(2)));
typedef __bf16 bf16x8 __attribute__((ext_vector_type(8)));
typedef __bf16 bf16x4 __attribute__((ext_vector_type(4)));

__device__ __forceinline__ float silu_f(float v) {
  return v * __builtin_amdgcn_rcpf(1.f + __expf(-v));
}

// ---------------------------------------------------------------------------
// Pack fp32 weight matrix [L][K][128] into MFMA-fragment order:
// out[((layer*ktn + kt)*8 + nt)*64 + lane][8], elem j = W[kt*32+(lane>>4)*8+j][nt*16+(lane&15)]
// ---------------------------------------------------------------------------
__global__ void pack_weights(const float* __restrict__ W, __bf16* __restrict__ out,
                             const int K, const int lstride, const int total) {
  const int idx = blockIdx.x * 256 + threadIdx.x;
  if (idx >= total) return;
  const int lane = idx & 63;
  const int nt = (idx >> 6) & 7;
  const int ktn = K >> 5;
  const int kt = (idx >> 9) % ktn;
  const int layer = (idx >> 9) / ktn;
  const int col = nt * 16 + (lane & 15);
  const int kb = kt * 32 + (lane >> 4) * 8;
  const float* src = W + (size_t)layer * lstride;
  __bf16* o = out + (size_t)idx * 8;
#pragma unroll
  for (int j = 0; j < 8; ++j) o[j] = (__bf16)src[(kb + j) * 128 + col];
}

// ---------------------------------------------------------------------------
// Pack Wm1 for the P/Q precompute (K=128, C=256).
// ---------------------------------------------------------------------------
__global__ void pack_w1pq(const float* __restrict__ Wm1, __bf16* __restrict__ out) {
  const int idx = blockIdx.x * 256 + threadIdx.x;   // total = NL*4*16*64 = 81920
  const int lane = idx & 63;
  const int nt = (idx >> 6) & 15;
  const int kt = (idx >> 10) & 3;
  const int layer = idx >> 12;
  const int c = nt * 16 + (lane & 15);
  const int kb = kt * 32 + (lane >> 4) * 8;
  const float* src = Wm1 + (size_t)layer * 257 * 128;
  __bf16* o = out + (size_t)idx * 8;
#pragma unroll
  for (int j = 0; j < 8; ++j) {
    const int k = kb + j;
    o[j] = (__bf16)((c < 128) ? src[k * 128 + c] : src[(128 + k) * 128 + (c - 128)]);
  }
}

// ---------------------------------------------------------------------------
__global__ void embed_kernel(const float* __restrict__ x, const float* __restrict__ embW,
                             const float* __restrict__ embB,
                             float* __restrict__ h, float* __restrict__ h0,
                             __bf16* __restrict__ hbf) {
  const int idx = blockIdx.x * 256 + threadIdx.x;
  const int n = idx >> 7, d = idx & 127;
  const float v = x[n] * embW[d] + embB[d];
  h[idx] = v;
  h0[idx] = v;
  hbf[idx] = (__bf16)v;
}

// ---------------------------------------------------------------------------
// CSR build.
// ---------------------------------------------------------------------------
__global__ void hist_kernel(const int* __restrict__ ei, int* __restrict__ deg) {
  const int e = blockIdx.x * 256 + threadIdx.x;
  atomicAdd(&deg[ei[NE + e]], 1);
}

__global__ void scan_kernel(const int* __restrict__ deg, int* __restrict__ rowstart) {
  __shared__ int part[1024];
  const int r = blockIdx.x, t = threadIdx.x;
  const int* d = deg + (size_t)r * NN;
  int* rs = rowstart + (size_t)r * NN;
  int loc[20];
  int cnt = 0;
#pragma unroll
  for (int j = 0; j < 20; ++j) {
    const int i = t * 20 + j;
    const int v = (i < NN) ? d[i] : 0;
    loc[j] = cnt; cnt += v;
  }
  part[t] = cnt;
  __syncthreads();
  for (int off = 1; off < 1024; off <<= 1) {
    const int v = (t >= off) ? part[t - off] : 0;
    __syncthreads();
    part[t] += v;
    __syncthreads();
  }
  const int excl = (t == 0) ? 0 : part[t - 1];
#pragma unroll
  for (int j = 0; j < 20; ++j) {
    const int i = t * 20 + j;
    if (i < NN) rs[i] = excl + loc[j];
  }
}

__global__ void fill_kernel(const int* __restrict__ ei, const int* __restrict__ rowstart,
                            int* __restrict__ cursor, int* __restrict__ eord) {
  const int e = blockIdx.x * 256 + threadIdx.x;
  const int d = ei[NE + e];
  const int p = atomicAdd(&cursor[d], 1);
  eord[rowstart[d] + p] = e;
}

// ---------------------------------------------------------------------------
// P/Q precompute (unchanged logic; explicit waitcnt removed — compiler
// inserts the lgkmcnt-only waits for the T1 ds dependency).
// ---------------------------------------------------------------------------
__global__ __launch_bounds__(256) void pq_kernel(
    const __bf16* __restrict__ hbf, const __bf16* __restrict__ pqw,
    __bf16* __restrict__ pq) {
  __shared__ __bf16 T1s[4][2048];
  const int t = threadIdx.x, w = t >> 6, l = t & 63;
  const int lr = l & 15, lg = l >> 4;
  const int wid = blockIdx.x * 4 + w;
  const int n0 = (wid >> 1) * 16;
  const int half = wid & 1;
  char* T1 = (char*)T1s[w];

  const int node = n0 + lr;
  bf16x8 bq[4];
#pragma unroll
  for (int kt = 0; kt < 4; ++kt)
    bq[kt] = *(const bf16x8*)(hbf + (size_t)node * 128 + kt * 32 + lg * 8);

  f32x4 acc[8];
#pragma unroll
  for (int nt = 0; nt < 8; ++nt) acc[nt] = (f32x4)0.f;
#pragma unroll
  for (int kt = 0; kt < 4; ++kt) {
#pragma unroll
    for (int nt = 0; nt < 8; ++nt) {
      const bf16x8 a = *(const bf16x8*)(pqw + ((size_t)((kt * 16 + half * 8 + nt) * 64 + l)) * 8);
      acc[nt] = __builtin_amdgcn_mfma_f32_16x16x32_bf16(a, bq[kt], acc[nt], 0, 0, 0);
    }
  }
#pragma unroll
  for (int nt = 0; nt < 8; ++nt) {
    bf16x4 v;
#pragma unroll
    for (int r = 0; r < 4; ++r) v[r] = (__bf16)acc[nt][r];
    *(bf16x4*)(T1 + ((lr * 256 + nt * 32 + lg * 8) ^ ((lr & 7) << 4))) = v;
  }
#pragma unroll
  for (int j = 0; j < 4; ++j) {
    const int row = j * 4 + lg;
    const uint4 v = *(const uint4*)(T1 + ((row * 256 + lr * 16) ^ ((row & 7) << 4)));
    *(uint4*)(pq + (size_t)(n0 + row) * 256 + half * 128 + lr * 8) = v;
  }
}

// ---------------------------------------------------------------------------
// Edge-message kernel v4: PERSISTENT waves with next-tile prefetch.
// grid = 256 blocks x 16 waves = 4096 waves over 10000 16-edge tiles.
// Per tile: m1 = P[dst]+Q[src]+dist*w1last+bm1 (fragment-ready) -> LN1 ->
// SiLU -> GEMM2 (W2^T in LDS x m1^T regs) -> LN2 -> SiLU -> T1 -> msg store.
// Next tile's ei/pos/pq loads are issued BEFORE current tile's compute.
// ---------------------------------------------------------------------------
__global__ __launch_bounds__(1024, 4) void edge_msg_kernel(
    const __bf16* __restrict__ pq, const float* __restrict__ pos,
    const int* __restrict__ ei, __bf16* __restrict__ msg,
    const __bf16* __restrict__ w2p, const float* __restrict__ w1last,
    const float* __restrict__ bm1, const float* __restrict__ gm1, const float* __restrict__ sm1,
    const float* __restrict__ bm2, const float* __restrict__ gm2, const float* __restrict__ sm2) {
  extern __shared__ char lds[];
  {
    const int t = threadIdx.x;
    uint4* d = (uint4*)lds;
    const uint4* s2 = (const uint4*)w2p;
    d[t] = s2[t];
    d[t + 1024] = s2[t + 1024];
  }
  __syncthreads();

  const int t = threadIdx.x, w = t >> 6, l = t & 63;
  const int lr = l & 15, lg = l >> 4;
  char* W2L = lds;
  char* T1  = lds + 32768 + w * 4096;

  const int NW = gridDim.x * 16;          // 4096 waves
  const int NT = NE / 16;                 // 10000 tiles
  int tile = blockIdx.x * 16 + w;

  // prologue: load tile's inputs
  int es = ei[tile * 16 + lr], ed = ei[NE + tile * 16 + lr];
  float dist;
  {
    const float dx = pos[ed * 3 + 0] - pos[es * 3 + 0];
    const float dy = pos[ed * 3 + 1] - pos[es * 3 + 1];
    const float dz = pos[ed * 3 + 2] - pos[es * 3 + 2];
    dist = sqrtf(dx * dx + dy * dy + dz * dz);
  }
  bf16x8 pA[4], qA[4];
#pragma unroll
  for (int kt = 0; kt < 4; ++kt) {
    pA[kt] = *(const bf16x8*)(pq + (size_t)ed * 256 + kt * 32 + lg * 8);
    qA[kt] = *(const bf16x8*)(pq + (size_t)es * 256 + 128 + kt * 32 + lg * 8);
  }

  while (true) {
    const int next = tile + NW;
    const bool more = (next < NT);
    // ---- prefetch next tile (issued before current compute; wave-uniform branch)
    float dist_n = 0.f;
    bf16x8 pA_n[4], qA_n[4];
    if (more) {
      const int es_n = ei[next * 16 + lr], ed_n = ei[NE + next * 16 + lr];
      const float dx = pos[ed_n * 3 + 0] - pos[es_n * 3 + 0];
      const float dy = pos[ed_n * 3 + 1] - pos[es_n * 3 + 1];
      const float dz = pos[ed_n * 3 + 2] - pos[es_n * 3 + 2];
      dist_n = sqrtf(dx * dx + dy * dy + dz * dz);
#pragma unroll
      for (int kt = 0; kt < 4; ++kt) {
        pA_n[kt] = *(const bf16x8*)(pq + (size_t)ed_n * 256 + kt * 32 + lg * 8);
        qA_n[kt] = *(const bf16x8*)(pq + (size_t)es_n * 256 + 128 + kt * 32 + lg * 8);
      }
    }
    // ---- current tile compute
    // m1: lane holds dims d = kt*32 + lg*8 + j
    float v[4][8];
#pragma unroll
    for (int kt = 0; kt < 4; ++kt) {
      const int d0 = kt * 32 + lg * 8;
      const f32x4 wl0 = *(const f32x4*)(w1last + d0), wl1 = *(const f32x4*)(w1last + d0 + 4);
      const f32x4 bb0 = *(const f32x4*)(bm1 + d0),    bb1 = *(const f32x4*)(bm1 + d0 + 4);
#pragma unroll
      for (int j = 0; j < 4; ++j) {
        v[kt][j]     = (float)pA[kt][j]     + (float)qA[kt][j]     + dist * wl0[j] + bb0[j];
        v[kt][j + 4] = (float)pA[kt][j + 4] + (float)qA[kt][j + 4] + dist * wl1[j] + bb1[j];
      }
    }
    // LN1 (row = edge lr; partners lane^16, lane^32)
    float s = 0.f, q = 0.f;
#pragma unroll
    for (int kt = 0; kt < 4; ++kt)
#pragma unroll
      for (int j = 0; j < 8; ++j) { const float x = v[kt][j]; s += x; q += x * x; }
    s += __shfl_xor(s, 16); q += __shfl_xor(q, 16);
    s += __shfl_xor(s, 32); q += __shfl_xor(q, 32);
    const float mu1 = s * 0.0078125f;
    const float rstd1 = rsqrtf(q * 0.0078125f - mu1 * mu1 + 1e-5f);
    bf16x8 bfrag[4];
#pragma unroll
    for (int kt = 0; kt < 4; ++kt) {
      const int d0 = kt * 32 + lg * 8;
      const f32x4 g0 = *(const f32x4*)(gm1 + d0), g1 = *(const f32x4*)(gm1 + d0 + 4);
      const f32x4 s0 = *(const f32x4*)(sm1 + d0), s1 = *(const f32x4*)(sm1 + d0 + 4);
      bf16x8 bf;
#pragma unroll
      for (int j = 0; j < 4; ++j) {
        bf[j]     = (__bf16)silu_f((v[kt][j]     - mu1) * rstd1 * g0[j] + s0[j]);
        bf[j + 4] = (__bf16)silu_f((v[kt][j + 4] - mu1) * rstd1 * g1[j] + s1[j]);
      }
      bfrag[kt] = bf;
    }
    // GEMM2 transposed
    f32x4 acc2[8];
#pragma unroll
    for (int nt = 0; nt < 8; ++nt)
      acc2[nt] = *(const f32x4*)(bm2 + nt * 16 + lg * 4);
#pragma unroll
    for (int kt = 0; kt < 4; ++kt) {
#pragma unroll
      for (int nt = 0; nt < 8; ++nt) {
        const bf16x8 a = *(const bf16x8*)(W2L + ((kt * 8 + nt) * 64 + l) * 16);
        acc2[nt] = __builtin_amdgcn_mfma_f32_16x16x32_bf16(a, bfrag[kt], acc2[nt], 0, 0, 0);
      }
    }
    // LN2
    float s2 = 0.f, q2 = 0.f;
#pragma unroll
    for (int nt = 0; nt < 8; ++nt)
#pragma unroll
      for (int r = 0; r < 4; ++r) { const float x = acc2[nt][r]; s2 += x; q2 += x * x; }
    s2 += __shfl_xor(s2, 16); q2 += __shfl_xor(q2, 16);
    s2 += __shfl_xor(s2, 32); q2 += __shfl_xor(q2, 32);
    const float mu2 = s2 * 0.0078125f;
    const float rstd2 = rsqrtf(q2 * 0.0078125f - mu2 * mu2 + 1e-5f);
#pragma unroll
    for (int nt = 0; nt < 8; ++nt) {
      const f32x4 g2 = *(const f32x4*)(gm2 + nt * 16 + lg * 4);
      const f32x4 b2 = *(const f32x4*)(sm2 + nt * 16 + lg * 4);
      bf16x4 pk;
#pragma unroll
      for (int r = 0; r < 4; ++r)
        pk[r] = (__bf16)silu_f((acc2[nt][r] - mu2) * rstd2 * g2[r] + b2[r]);
      *(bf16x4*)(T1 + ((lr * 256 + nt * 32 + lg * 8) ^ ((lr & 7) << 4))) = pk;
    }
    // msg store (compiler inserts lgkmcnt for the T1 dependency; vm prefetches stay in flight)
    char* mbase = (char*)(msg + (size_t)(tile * 16) * 128);
#pragma unroll
    for (int j = 0; j < 4; ++j) {
      const int row = j * 4 + lg;
      const uint4 val = *(const uint4*)(T1 + ((row * 256 + lr * 16) ^ ((row & 7) << 4)));
      *(uint4*)(mbase + j * 1024 + l * 16) = val;
    }
    if (!more) break;
    tile = next;
    dist = dist_n;
#pragma unroll
    for (int kt = 0; kt < 4; ++kt) { pA[kt] = pA_n[kt]; qA[kt] = qA_n[kt]; }
  }
}

// ---------------------------------------------------------------------------
// CSR gather at full occupancy (unchanged).
// ---------------------------------------------------------------------------
__global__ void gather_kernel(const __bf16* __restrict__ msg,
                              const int* __restrict__ rowstart, const int* __restrict__ deg,
                              const int* __restrict__ eord, float* __restrict__ agg) {
  const int t = blockIdx.x * 256 + threadIdx.x;
  const int n = t >> 6, pd = t & 63;
  const int s = rowstart[n], dg = deg[n];
  float a0 = 0.f, a1 = 0.f;
  int i = 0;
  for (; i + 2 <= dg; i += 2) {
    const unsigned v0 = *(const unsigned*)(msg + (size_t)eord[s + i] * 128 + pd * 2);
    const unsigned v1 = *(const unsigned*)(msg + (size_t)eord[s + i + 1] * 128 + pd * 2);
    a0 += __uint_as_float(v0 << 16) + __uint_as_float(v1 << 16);
    a1 += __uint_as_float(v0 & 0xFFFF0000u) + __uint_as_float(v1 & 0xFFFF0000u);
  }
  if (i < dg) {
    const unsigned v0 = *(const unsigned*)(msg + (size_t)eord[s + i] * 128 + pd * 2);
    a0 += __uint_as_float(v0 << 16);
    a1 += __uint_as_float(v0 & 0xFFFF0000u);
  }
  f32x2 o; o[0] = a0; o[1] = a1;
  *(f32x2*)(agg + (size_t)n * 128 + pd * 2) = o;
}

// ---------------------------------------------------------------------------
// Node-update MLP (unchanged).
// ---------------------------------------------------------------------------
__global__ __launch_bounds__(256) void update_kernel(
    float* __restrict__ h, const float* __restrict__ aggv, __bf16* __restrict__ hbf,
    float* __restrict__ h0, const int mode,
    const __bf16* __restrict__ w1p, const __bf16* __restrict__ w2p,
    const float* __restrict__ bu1, const float* __restrict__ gu1, const float* __restrict__ su1,
    const float* __restrict__ bu2, const float* __restrict__ gu2, const float* __restrict__ su2) {
  __shared__ __bf16 T1s[4][16 * 128];
  const int t = threadIdx.x, w = t >> 6, l = t & 63;
  const int lr = l & 15, lg = l >> 4;
  char* T1 = (char*)T1s[w];
  const int n0 = blockIdx.x * 64 + w * 16;
  const int n = n0 + lr;
  const int valid = (n < NN);
  const int nc = valid ? n : 0;

  bf16x8 ah[4], af[4];
#pragma unroll
  for (int kt = 0; kt < 4; ++kt) {
    ah[kt] = *(const bf16x8*)(hbf + (size_t)nc * 128 + kt * 32 + lg * 8);
    const f32x4* pA = (const f32x4*)(aggv + (size_t)nc * 128 + kt * 32 + lg * 8);
    const f32x4 u0 = pA[0], u1 = pA[1];
#pragma unroll
    for (int j = 0; j < 4; ++j) {
      af[kt][j] = (__bf16)u0[j];
      af[kt][j + 4] = (__bf16)u1[j];
    }
  }
  f32x4 acc[8];
#pragma unroll
  for (int nt = 0; nt < 8; ++nt) {
    const float bb = bu1[nt * 16 + lr];
#pragma unroll
    for (int r = 0; r < 4; ++r) acc[nt][r] = bb;
  }
#pragma unroll
  for (int kt = 0; kt < 8; ++kt) {
    const bf16x8 a = (kt < 4) ? ah[kt] : af[kt - 4];
#pragma unroll
    for (int nt = 0; nt < 8; ++nt) {
      const bf16x8 b = *(const bf16x8*)(w1p + ((size_t)((kt * 8 + nt) * 64 + l)) * 8);
      acc[nt] = __builtin_amdgcn_mfma_f32_16x16x32_bf16(a, b, acc[nt], 0, 0, 0);
    }
  }
  {
    float g1c[8], s1c[8];
#pragma unroll
    for (int nt = 0; nt < 8; ++nt) { g1c[nt] = gu1[nt * 16 + lr]; s1c[nt] = su1[nt * 16 + lr]; }
#pragma unroll
    for (int r = 0; r < 4; ++r) {
      float s = 0.f, q = 0.f;
#pragma unroll
      for (int nt = 0; nt < 8; ++nt) { const float v = acc[nt][r]; s += v; q += v * v; }
#pragma unroll
      for (int m = 1; m < 16; m <<= 1) { s += __shfl_xor(s, m); q += __shfl_xor(q, m); }
      const float mu = s * 0.0078125f;
      const float rstd = rsqrtf(q * 0.0078125f - mu * mu + 1e-5f);
      const int row = lg * 4 + r;
#pragma unroll
      for (int nt = 0; nt < 8; ++nt) {
        float v = (acc[nt][r] - mu) * rstd * g1c[nt] + s1c[nt];
        v = silu_f(v);
        const int col = nt * 16 + lr;
        *(__bf16*)(T1 + ((row * 256 + col * 2) ^ ((row & 7) << 4))) = (__bf16)v;
      }
    }
  }
  __syncthreads();
  f32x4 acc2[8];
#pragma unroll
  for (int nt = 0; nt < 8; ++nt) {
    const float bb = bu2[nt * 16 + lr];
#pragma unroll
    for (int r = 0; r < 4; ++r) acc2[nt][r] = bb;
  }
#pragma unroll
  for (int kt = 0; kt < 4; ++kt) {
    const bf16x8 a = *(const bf16x8*)(T1 + ((lr * 256 + kt * 64 + lg * 16) ^ ((lr & 7) << 4)));
#pragma unroll
    for (int nt = 0; nt < 8; ++nt) {
      const bf16x8 b = *(const bf16x8*)(w2p + ((size_t)((kt * 8 + nt) * 64 + l)) * 8);
      acc2[nt] = __builtin_amdgcn_mfma_f32_16x16x32_bf16(a, b, acc2[nt], 0, 0, 0);
    }
  }
  {
    float g2c[8], s2c[8];
#pragma unroll
    for (int nt = 0; nt < 8; ++nt) { g2c[nt] = gu2[nt * 16 + lr]; s2c[nt] = su2[nt * 16 + lr]; }
#pragma unroll
    for (int r = 0; r < 4; ++r) {
      float s = 0.f, q = 0.f;
#pragma unroll
      for (int nt = 0; nt < 8; ++nt) { const float v = acc2[nt][r]; s += v; q += v * v; }
#pragma unroll
      for (int m = 1; m < 16; m <<= 1) { s += __shfl_xor(s, m); q += __shfl_xor(q, m); }
      const float mu = s * 0.0078125f;
      const float rstd = rsqrtf(q * 0.0078125f - mu * mu + 1e-5f);
      const int row = lg * 4 + r;
      const int nn = n0 + row;
      if (nn < NN) {
#pragma unroll
        for (int nt = 0; nt < 8; ++nt) {
          const int col = nt * 16 + lr;
          float v = (acc2[nt][r] - mu) * rstd * g2c[nt] + s2c[nt];
          v = silu_f(v);
          if (mode) v += h0[(size_t)nn * 128 + col];
          h[(size_t)nn * 128 + col] = v;
          hbf[(size_t)nn * 128 + col] = (__bf16)v;
          if (mode) h0[(size_t)nn * 128 + col] = v;
        }
      }
    }
  }
}

// ---------------------------------------------------------------------------
__global__ void pool_kernel(const float* __restrict__ h, const int* __restrict__ bid,
                            float* __restrict__ pooled) {
  const int d = threadIdx.x;
  const int n0 = blockIdx.x * 32;
  const int nend = (n0 + 32 < NN) ? (n0 + 32) : NN;
  float acc = 0.f;
  int cur = bid[n0];
  for (int n = n0; n < nend; ++n) {
    const int b = bid[n];
    if (b != cur) { atomicAdd(&pooled[cur * 128 + d], acc); acc = 0.f; cur = b; }
    acc += h[(size_t)n * 128 + d];
  }
  atomicAdd(&pooled[cur * 128 + d], acc);
}

__global__ void head_kernel(const float* __restrict__ pooled,
                            const float* __restrict__ W1, const float* __restrict__ b1,
                            const float* __restrict__ W2, const float* __restrict__ b2,
                            float* __restrict__ out) {
  __shared__ float buf[2];
  const int b = blockIdx.x, t = threadIdx.x;
  float s = b1[t];
  for (int k = 0; k < 128; ++k) s += pooled[b * 128 + k] * W1[k * 128 + t];
  s = fmaxf(s, 0.f) * W2[t];
#pragma unroll
  for (int m = 32; m >= 1; m >>= 1) s += __shfl_down(s, m);
  if ((t & 63) == 0) buf[t >> 6] = s;
  __syncthreads();
  if (t == 0) out[b] = buf[0] + buf[1] + b2[0];
}

// ---------------------------------------------------------------------------
extern "C" void kernel_launch(void* const* d_in, const int* in_sizes, int n_in,
                              void* d_out, int out_size, void* d_ws, size_t ws_size,
                              hipStream_t stream) {
  const float* x   = (const float*)d_in[0];
  const float* pos = (const float*)d_in[1];
  const int* eis[4] = {(const int*)d_in[2], (const int*)d_in[3],
                       (const int*)d_in[4], (const int*)d_in[5]};
  const int* bid = (const int*)d_in[6];
  const float* embW = (const float*)d_in[7];
  const float* embB = (const float*)d_in[8];
  const float* Wm1 = (const float*)d_in[9];
  const float* bm1 = (const float*)d_in[10];
  const float* gm1 = (const float*)d_in[11];
  const float* sm1 = (const float*)d_in[12];
  const float* Wm2 = (const float*)d_in[13];
  const float* bm2 = (const float*)d_in[14];
  const float* gm2 = (const float*)d_in[15];
  const float* sm2 = (const float*)d_in[16];
  const float* Wu1 = (const float*)d_in[17];
  const float* bu1 = (const float*)d_in[18];
  const float* gu1 = (const float*)d_in[19];
  const float* su1 = (const float*)d_in[20];
  const float* Wu2 = (const float*)d_in[21];
  const float* bu2 = (const float*)d_in[22];
  const float* gu2 = (const float*)d_in[23];
  const float* su2 = (const float*)d_in[24];
  const float* pW1 = (const float*)d_in[25];
  const float* pb1 = (const float*)d_in[26];
  const float* pW2 = (const float*)d_in[27];
  const float* pb2 = (const float*)d_in[28];
  float* out = (float*)d_out;

  char* wp = (char*)d_ws;
  float* h = (float*)wp;      wp += (size_t)NN * 128 * 4;
  float* h0 = (float*)wp;     wp += (size_t)NN * 128 * 4;
  float* agg = (float*)wp;    wp += (size_t)NN * 128 * 4;
  float* pooled = (float*)wp; wp += 16 * 128 * 4;
  __bf16* hbf = (__bf16*)wp;  wp += (size_t)NN * 128 * 2;
  __bf16* pq = (__bf16*)wp;   wp += (size_t)NN * 256 * 2;
  __bf16* msg = (__bf16*)wp;  wp += (size_t)NE * 128 * 2;
  __bf16* pqw = (__bf16*)wp;  wp += (size_t)NL * 32768 * 2;
  __bf16* w2p = (__bf16*)wp;  wp += (size_t)NL * 16384 * 2;
  __bf16* wu1p = (__bf16*)wp; wp += (size_t)NL * 32768 * 2;
  __bf16* wu2p = (__bf16*)wp; wp += (size_t)NL * 16384 * 2;
  int* deg = (int*)wp;        wp += (size_t)4 * NN * 4;
  int* cursor = (int*)wp;     wp += (size_t)4 * NN * 4;
  int* rowstart = (int*)wp;   wp += (size_t)4 * NN * 4;
  int* eord = (int*)wp;       wp += (size_t)4 * NE * 4;

  static int lds_attr_set = 0;
  if (!lds_attr_set) {
    hipFuncSetAttribute((const void*)edge_msg_kernel,
                        hipFuncAttributeMaxDynamicSharedMemorySize, 98304);
    lds_attr_set = 1;
  }

  pack_w1pq<<<320, 256, 0, stream>>>(Wm1, pqw);
  pack_weights<<<160, 256, 0, stream>>>(Wm2, w2p, 128, 128 * 128, NL * 4 * 8 * 64);
  pack_weights<<<320, 256, 0, stream>>>(Wu1, wu1p, 256, 256 * 128, NL * 8 * 8 * 64);
  pack_weights<<<160, 256, 0, stream>>>(Wu2, wu2p, 128, 128 * 128, NL * 4 * 8 * 64);

  hipMemsetAsync(deg, 0, (size_t)8 * NN * 4, stream);
  embed_kernel<<<(NN * 128) / 256, 256, 0, stream>>>(x, embW, embB, h, h0, hbf);
  for (int r = 0; r < 4; ++r)
    hist_kernel<<<NE / 256, 256, 0, stream>>>(eis[r], deg + (size_t)r * NN);
  scan_kernel<<<4, 1024, 0, stream>>>(deg, rowstart);
  for (int r = 0; r < 4; ++r)
    fill_kernel<<<NE / 256, 256, 0, stream>>>(eis[r], rowstart + (size_t)r * NN,
                                              cursor + (size_t)r * NN, eord + (size_t)r * NE);

  for (int layer = 0; layer < 5; ++layer) {
    for (int r = 0; r < 4; ++r) {
      const int i = layer * 4 + r;
      pq_kernel<<<625, 256, 0, stream>>>(hbf, pqw + (size_t)i * 32768, pq);
      edge_msg_kernel<<<256, 1024, 98304, stream>>>(
          pq, pos, eis[r], msg,
          w2p + (size_t)i * 16384,
          Wm1 + (size_t)i * 257 * 128 + 256 * 128,
          bm1 + i * 128, gm1 + i * 128, sm1 + i * 128,
          bm2 + i * 128, gm2 + i * 128, sm2 + i * 128);
      gather_kernel<<<(NN * 64) / 256, 256, 0, stream>>>(
          msg, rowstart + (size_t)r * NN, deg + (size_t)r * NN, eord + (size_t)r * NE, agg);
      update_kernel<<<(NN + 63) / 64, 256, 0, stream>>>(
          h, agg, hbf, h0, (r == 3) ? 1 : 0,
          wu1p + (size_t)i * 32768, wu2p + (size_t)i * 16384,
          bu1 + i * 128, gu1 + i * 128, su1 + i * 128,
          bu2 + i * 128, gu2 + i * 128, su2 + i * 128);
    }
  }

  hipMemsetAsync(pooled, 0, 16 * 128 * 4, stream);
  pool_kernel<<<(NN + 31) / 32, 128, 0, stream>>>(h, bid, pooled);
  head_kernel<<<16, 128, 0, stream>>>(pooled, pW1, pb1, pW2, pb2, out);
}

// Round 9
// 1900.292 us; speedup vs baseline: 4.0593x; 4.0593x over previous
//
#include <hip/hip_runtime.h>

#define NN 20000      // nodes
#define NE 160000     // edges per edge set
#define NL 20         // EGNN layer calls (4*DEPTH)

typedef float f32x4 __attribute__((ext_vector_type(4)));
typedef float f32x2 __attribute__((ext_vector_type(2)));
typedef __bf16 bf16x8 __attribute__((ext_vector_type(8)));
typedef __bf16 bf16x4 __attribute__((ext_vector_type(4)));

__device__ __forceinline__ float silu_f(float v) {
  return v * __builtin_amdgcn_rcpf(1.f + __expf(-v));
}

// ---------------------------------------------------------------------------
// Pack fp32 weight matrix [L][K][128] into MFMA-fragment order:
// out[((layer*ktn + kt)*8 + nt)*64 + lane][8], elem j = W[kt*32+(lane>>4)*8+j][nt*16+(lane&15)]
// ---------------------------------------------------------------------------
__global__ void pack_weights(const float* __restrict__ W, __bf16* __restrict__ out,
                             const int K, const int lstride, const int total) {
  const int idx = blockIdx.x * 256 + threadIdx.x;
  if (idx >= total) return;
  const int lane = idx & 63;
  const int nt = (idx >> 6) & 7;
  const int ktn = K >> 5;
  const int kt = (idx >> 9) % ktn;
  const int layer = (idx >> 9) / ktn;
  const int col = nt * 16 + (lane & 15);
  const int kb = kt * 32 + (lane >> 4) * 8;
  const float* src = W + (size_t)layer * lstride;
  __bf16* o = out + (size_t)idx * 8;
#pragma unroll
  for (int j = 0; j < 8; ++j) o[j] = (__bf16)src[(kb + j) * 128 + col];
}

// ---------------------------------------------------------------------------
// Pack Wm1 for the P/Q precompute (K=128, C=256).
// ---------------------------------------------------------------------------
__global__ void pack_w1pq(const float* __restrict__ Wm1, __bf16* __restrict__ out) {
  const int idx = blockIdx.x * 256 + threadIdx.x;   // total = NL*4*16*64 = 81920
  const int lane = idx & 63;
  const int nt = (idx >> 6) & 15;
  const int kt = (idx >> 10) & 3;
  const int layer = idx >> 12;
  const int c = nt * 16 + (lane & 15);
  const int kb = kt * 32 + (lane >> 4) * 8;
  const float* src = Wm1 + (size_t)layer * 257 * 128;
  __bf16* o = out + (size_t)idx * 8;
#pragma unroll
  for (int j = 0; j < 8; ++j) {
    const int k = kb + j;
    o[j] = (__bf16)((c < 128) ? src[k * 128 + c] : src[(128 + k) * 128 + (c - 128)]);
  }
}

// ---------------------------------------------------------------------------
// embed: h fp32 is NOT written (dead until pool; final update produces it).
// ---------------------------------------------------------------------------
__global__ void embed_kernel(const float* __restrict__ x, const float* __restrict__ embW,
                             const float* __restrict__ embB,
                             float* __restrict__ h0, __bf16* __restrict__ hbf) {
  const int idx = blockIdx.x * 256 + threadIdx.x;
  const int n = idx >> 7, d = idx & 127;
  const float v = x[n] * embW[d] + embB[d];
  h0[idx] = v;
  hbf[idx] = (__bf16)v;
}

// ---------------------------------------------------------------------------
// CSR build.
// ---------------------------------------------------------------------------
__global__ void hist_kernel(const int* __restrict__ ei, int* __restrict__ deg) {
  const int e = blockIdx.x * 256 + threadIdx.x;
  atomicAdd(&deg[ei[NE + e]], 1);
}

__global__ void scan_kernel(const int* __restrict__ deg, int* __restrict__ rowstart) {
  __shared__ int part[1024];
  const int r = blockIdx.x, t = threadIdx.x;
  const int* d = deg + (size_t)r * NN;
  int* rs = rowstart + (size_t)r * NN;
  int loc[20];
  int cnt = 0;
#pragma unroll
  for (int j = 0; j < 20; ++j) {
    const int i = t * 20 + j;
    const int v = (i < NN) ? d[i] : 0;
    loc[j] = cnt; cnt += v;
  }
  part[t] = cnt;
  __syncthreads();
  for (int off = 1; off < 1024; off <<= 1) {
    const int v = (t >= off) ? part[t - off] : 0;
    __syncthreads();
    part[t] += v;
    __syncthreads();
  }
  const int excl = (t == 0) ? 0 : part[t - 1];
#pragma unroll
  for (int j = 0; j < 20; ++j) {
    const int i = t * 20 + j;
    if (i < NN) rs[i] = excl + loc[j];
  }
}

__global__ void fill_kernel(const int* __restrict__ ei, const int* __restrict__ rowstart,
                            int* __restrict__ cursor, int* __restrict__ eord) {
  const int e = blockIdx.x * 256 + threadIdx.x;
  const int d = ei[NE + e];
  const int p = atomicAdd(&cursor[d], 1);
  eord[rowstart[d] + p] = e;
}

// ---------------------------------------------------------------------------
// P/Q precompute.
// ---------------------------------------------------------------------------
__global__ __launch_bounds__(256) void pq_kernel(
    const __bf16* __restrict__ hbf, const __bf16* __restrict__ pqw,
    __bf16* __restrict__ pq) {
  __shared__ __bf16 T1s[4][2048];
  const int t = threadIdx.x, w = t >> 6, l = t & 63;
  const int lr = l & 15, lg = l >> 4;
  const int wid = blockIdx.x * 4 + w;
  const int n0 = (wid >> 1) * 16;
  const int half = wid & 1;
  char* T1 = (char*)T1s[w];

  const int node = n0 + lr;
  bf16x8 bq[4];
#pragma unroll
  for (int kt = 0; kt < 4; ++kt)
    bq[kt] = *(const bf16x8*)(hbf + (size_t)node * 128 + kt * 32 + lg * 8);

  f32x4 acc[8];
#pragma unroll
  for (int nt = 0; nt < 8; ++nt) acc[nt] = (f32x4)0.f;
#pragma unroll
  for (int kt = 0; kt < 4; ++kt) {
#pragma unroll
    for (int nt = 0; nt < 8; ++nt) {
      const bf16x8 a = *(const bf16x8*)(pqw + ((size_t)((kt * 16 + half * 8 + nt) * 64 + l)) * 8);
      acc[nt] = __builtin_amdgcn_mfma_f32_16x16x32_bf16(a, bq[kt], acc[nt], 0, 0, 0);
    }
  }
#pragma unroll
  for (int nt = 0; nt < 8; ++nt) {
    bf16x4 v;
#pragma unroll
    for (int r = 0; r < 4; ++r) v[r] = (__bf16)acc[nt][r];
    *(bf16x4*)(T1 + ((lr * 256 + nt * 32 + lg * 8) ^ ((lr & 7) << 4))) = v;
  }
#pragma unroll
  for (int j = 0; j < 4; ++j) {
    const int row = j * 4 + lg;
    const uint4 v = *(const uint4*)(T1 + ((row * 256 + lr * 16) ^ ((row & 7) << 4)));
    *(uint4*)(pq + (size_t)(n0 + row) * 256 + half * 128 + lr * 8) = v;
  }
}

// ---------------------------------------------------------------------------
// Edge-message kernel (R7 body, T1 halved to 2KB/wave -> 64KB block LDS ->
// 2 blocks/CU = 8 waves/SIMD). Output dims processed in two 64-dim passes.
// ---------------------------------------------------------------------------
__global__ __launch_bounds__(1024, 4) void edge_msg_kernel(
    const __bf16* __restrict__ pq, const float* __restrict__ pos,
    const int* __restrict__ ei, __bf16* __restrict__ msg,
    const __bf16* __restrict__ w2p, const float* __restrict__ w1last,
    const float* __restrict__ bm1, const float* __restrict__ gm1, const float* __restrict__ sm1,
    const float* __restrict__ bm2, const float* __restrict__ gm2, const float* __restrict__ sm2) {
  extern __shared__ char lds[];
  {
    const int t = threadIdx.x;
    uint4* d = (uint4*)lds;
    const uint4* s2 = (const uint4*)w2p;
    d[t] = s2[t];
    d[t + 1024] = s2[t + 1024];
  }
  __syncthreads();

  const int t = threadIdx.x, w = t >> 6, l = t & 63;
  const int lr = l & 15, lg = l >> 4;
  char* W2L = lds;                        // 32 KB
  char* T1  = lds + 32768 + w * 2048;     // 2 KB per wave

  const int e0 = blockIdx.x * 256 + w * 16;
  const int es = ei[e0 + lr], ed = ei[NE + e0 + lr];
  const float dx = pos[ed * 3 + 0] - pos[es * 3 + 0];
  const float dy = pos[ed * 3 + 1] - pos[es * 3 + 1];
  const float dz = pos[ed * 3 + 2] - pos[es * 3 + 2];
  const float dist = sqrtf(dx * dx + dy * dy + dz * dz);

  // m1: lane holds dims d = kt*32 + lg*8 + j (fragment-ready)
  float v[4][8];
#pragma unroll
  for (int kt = 0; kt < 4; ++kt) {
    const int d0 = kt * 32 + lg * 8;
    const bf16x8 pA = *(const bf16x8*)(pq + (size_t)ed * 256 + d0);
    const bf16x8 qA = *(const bf16x8*)(pq + (size_t)es * 256 + 128 + d0);
    const f32x4 wl0 = *(const f32x4*)(w1last + d0), wl1 = *(const f32x4*)(w1last + d0 + 4);
    const f32x4 bb0 = *(const f32x4*)(bm1 + d0),    bb1 = *(const f32x4*)(bm1 + d0 + 4);
#pragma unroll
    for (int j = 0; j < 4; ++j) {
      v[kt][j]     = (float)pA[j]     + (float)qA[j]     + dist * wl0[j] + bb0[j];
      v[kt][j + 4] = (float)pA[j + 4] + (float)qA[j + 4] + dist * wl1[j] + bb1[j];
    }
  }
  // LN1 (row = edge lr; partners lane^16, lane^32)
  float s = 0.f, q = 0.f;
#pragma unroll
  for (int kt = 0; kt < 4; ++kt)
#pragma unroll
    for (int j = 0; j < 8; ++j) { const float x = v[kt][j]; s += x; q += x * x; }
  s += __shfl_xor(s, 16); q += __shfl_xor(q, 16);
  s += __shfl_xor(s, 32); q += __shfl_xor(q, 32);
  const float mu1 = s * 0.0078125f;
  const float rstd1 = rsqrtf(q * 0.0078125f - mu1 * mu1 + 1e-5f);
  bf16x8 bfrag[4];
#pragma unroll
  for (int kt = 0; kt < 4; ++kt) {
    const int d0 = kt * 32 + lg * 8;
    const f32x4 g0 = *(const f32x4*)(gm1 + d0), g1 = *(const f32x4*)(gm1 + d0 + 4);
    const f32x4 s0 = *(const f32x4*)(sm1 + d0), s1 = *(const f32x4*)(sm1 + d0 + 4);
    bf16x8 bf;
#pragma unroll
    for (int j = 0; j < 4; ++j) {
      bf[j]     = (__bf16)silu_f((v[kt][j]     - mu1) * rstd1 * g0[j] + s0[j]);
      bf[j + 4] = (__bf16)silu_f((v[kt][j + 4] - mu1) * rstd1 * g1[j] + s1[j]);
    }
    bfrag[kt] = bf;
  }
  // GEMM2 transposed: D[d2 = nt*16+lg*4+r][edge = lr]
  f32x4 acc2[8];
#pragma unroll
  for (int nt = 0; nt < 8; ++nt)
    acc2[nt] = *(const f32x4*)(bm2 + nt * 16 + lg * 4);
#pragma unroll
  for (int kt = 0; kt < 4; ++kt) {
#pragma unroll
    for (int nt = 0; nt < 8; ++nt) {
      const bf16x8 a = *(const bf16x8*)(W2L + ((kt * 8 + nt) * 64 + l) * 16);
      acc2[nt] = __builtin_amdgcn_mfma_f32_16x16x32_bf16(a, bfrag[kt], acc2[nt], 0, 0, 0);
    }
  }
  // LN2
  float s2 = 0.f, q2 = 0.f;
#pragma unroll
  for (int nt = 0; nt < 8; ++nt)
#pragma unroll
    for (int r = 0; r < 4; ++r) { const float x = acc2[nt][r]; s2 += x; q2 += x * x; }
  s2 += __shfl_xor(s2, 16); q2 += __shfl_xor(q2, 16);
  s2 += __shfl_xor(s2, 32); q2 += __shfl_xor(q2, 32);
  const float mu2 = s2 * 0.0078125f;
  const float rstd2 = rsqrtf(q2 * 0.0078125f - mu2 * mu2 + 1e-5f);
  // SiLU -> msg via two 64-dim passes through the 2KB T1
#pragma unroll
  for (int hh = 0; hh < 2; ++hh) {
#pragma unroll
    for (int nt4 = 0; nt4 < 4; ++nt4) {
      const int nt = hh * 4 + nt4;
      const f32x4 g2 = *(const f32x4*)(gm2 + nt * 16 + lg * 4);
      const f32x4 b2 = *(const f32x4*)(sm2 + nt * 16 + lg * 4);
      bf16x4 pk;
#pragma unroll
      for (int r = 0; r < 4; ++r)
        pk[r] = (__bf16)silu_f((acc2[nt][r] - mu2) * rstd2 * g2[r] + b2[r]);
      *(bf16x4*)(T1 + ((lr * 128 + nt4 * 32 + lg * 8) ^ ((lr & 7) << 4))) = pk;
    }
    // store this 64-dim half: 16 edges x 128B (one full cache line each)
#pragma unroll
    for (int j = 0; j < 2; ++j) {
      const int e8 = j * 8 + (l >> 3);
      const uint4 val = *(const uint4*)(T1 + ((e8 * 128 + (l & 7) * 16) ^ ((e8 & 7) << 4)));
      *(uint4*)((char*)msg + (size_t)(e0 + e8) * 256 + hh * 128 + (l & 7) * 16) = val;
    }
  }
}

// ---------------------------------------------------------------------------
// CSR gather at full occupancy -> bf16 agg (update's MFMA consumes bf16 anyway).
// ---------------------------------------------------------------------------
__global__ void gather_kernel(const __bf16* __restrict__ msg,
                              const int* __restrict__ rowstart, const int* __restrict__ deg,
                              const int* __restrict__ eord, __bf16* __restrict__ aggb) {
  const int t = blockIdx.x * 256 + threadIdx.x;
  const int n = t >> 6, pd = t & 63;
  const int s = rowstart[n], dg = deg[n];
  float a0 = 0.f, a1 = 0.f;
  int i = 0;
  for (; i + 2 <= dg; i += 2) {
    const unsigned v0 = *(const unsigned*)(msg + (size_t)eord[s + i] * 128 + pd * 2);
    const unsigned v1 = *(const unsigned*)(msg + (size_t)eord[s + i + 1] * 128 + pd * 2);
    a0 += __uint_as_float(v0 << 16) + __uint_as_float(v1 << 16);
    a1 += __uint_as_float(v0 & 0xFFFF0000u) + __uint_as_float(v1 & 0xFFFF0000u);
  }
  if (i < dg) {
    const unsigned v0 = *(const unsigned*)(msg + (size_t)eord[s + i] * 128 + pd * 2);
    a0 += __uint_as_float(v0 << 16);
    a1 += __uint_as_float(v0 & 0xFFFF0000u);
  }
  __bf16 o0 = (__bf16)a0, o1 = (__bf16)a1;
  unsigned pk = ((unsigned)*(unsigned short*)&o0) | (((unsigned)*(unsigned short*)&o1) << 16);
  *(unsigned*)(aggb + (size_t)n * 128 + pd * 2) = pk;
}

// ---------------------------------------------------------------------------
// Node-update MLP. mode: bit0 = residual (+h0, update h0), bit1 = final
// (write h fp32 for pool; skip hbf/h0).
// ---------------------------------------------------------------------------
__global__ __launch_bounds__(256) void update_kernel(
    float* __restrict__ h, const __bf16* __restrict__ aggb, __bf16* __restrict__ hbf,
    float* __restrict__ h0, const int mode,
    const __bf16* __restrict__ w1p, const __bf16* __restrict__ w2p,
    const float* __restrict__ bu1, const float* __restrict__ gu1, const float* __restrict__ su1,
    const float* __restrict__ bu2, const float* __restrict__ gu2, const float* __restrict__ su2) {
  __shared__ __bf16 T1s[4][16 * 128];
  const int t = threadIdx.x, w = t >> 6, l = t & 63;
  const int lr = l & 15, lg = l >> 4;
  char* T1 = (char*)T1s[w];
  const int n0 = blockIdx.x * 64 + w * 16;
  const int n = n0 + lr;
  const int valid = (n < NN);
  const int nc = valid ? n : 0;

  bf16x8 ah[4], af[4];
#pragma unroll
  for (int kt = 0; kt < 4; ++kt) {
    ah[kt] = *(const bf16x8*)(hbf + (size_t)nc * 128 + kt * 32 + lg * 8);
    af[kt] = *(const bf16x8*)(aggb + (size_t)nc * 128 + kt * 32 + lg * 8);
  }
  f32x4 acc[8];
#pragma unroll
  for (int nt = 0; nt < 8; ++nt) {
    const float bb = bu1[nt * 16 + lr];
#pragma unroll
    for (int r = 0; r < 4; ++r) acc[nt][r] = bb;
  }
#pragma unroll
  for (int kt = 0; kt < 8; ++kt) {
    const bf16x8 a = (kt < 4) ? ah[kt] : af[kt - 4];
#pragma unroll
    for (int nt = 0; nt < 8; ++nt) {
      const bf16x8 b = *(const bf16x8*)(w1p + ((size_t)((kt * 8 + nt) * 64 + l)) * 8);
      acc[nt] = __builtin_amdgcn_mfma_f32_16x16x32_bf16(a, b, acc[nt], 0, 0, 0);
    }
  }
  {
    float g1c[8], s1c[8];
#pragma unroll
    for (int nt = 0; nt < 8; ++nt) { g1c[nt] = gu1[nt * 16 + lr]; s1c[nt] = su1[nt * 16 + lr]; }
#pragma unroll
    for (int r = 0; r < 4; ++r) {
      float s = 0.f, q = 0.f;
#pragma unroll
      for (int nt = 0; nt < 8; ++nt) { const float v = acc[nt][r]; s += v; q += v * v; }
#pragma unroll
      for (int m = 1; m < 16; m <<= 1) { s += __shfl_xor(s, m); q += __shfl_xor(q, m); }
      const float mu = s * 0.0078125f;
      const float rstd = rsqrtf(q * 0.0078125f - mu * mu + 1e-5f);
      const int row = lg * 4 + r;
#pragma unroll
      for (int nt = 0; nt < 8; ++nt) {
        float v = (acc[nt][r] - mu) * rstd * g1c[nt] + s1c[nt];
        v = silu_f(v);
        const int col = nt * 16 + lr;
        *(__bf16*)(T1 + ((row * 256 + col * 2) ^ ((row & 7) << 4))) = (__bf16)v;
      }
    }
  }
  f32x4 acc2[8];
#pragma unroll
  for (int nt = 0; nt < 8; ++nt) {
    const float bb = bu2[nt * 16 + lr];
#pragma unroll
    for (int r = 0; r < 4; ++r) acc2[nt][r] = bb;
  }
#pragma unroll
  for (int kt = 0; kt < 4; ++kt) {
    const bf16x8 a = *(const bf16x8*)(T1 + ((lr * 256 + kt * 64 + lg * 16) ^ ((lr & 7) << 4)));
#pragma unroll
    for (int nt = 0; nt < 8; ++nt) {
      const bf16x8 b = *(const bf16x8*)(w2p + ((size_t)((kt * 8 + nt) * 64 + l)) * 8);
      acc2[nt] = __builtin_amdgcn_mfma_f32_16x16x32_bf16(a, b, acc2[nt], 0, 0, 0);
    }
  }
  {
    float g2c[8], s2c[8];
#pragma unroll
    for (int nt = 0; nt < 8; ++nt) { g2c[nt] = gu2[nt * 16 + lr]; s2c[nt] = su2[nt * 16 + lr]; }
#pragma unroll
    for (int r = 0; r < 4; ++r) {
      float s = 0.f, q = 0.f;
#pragma unroll
      for (int nt = 0; nt < 8; ++nt) { const float v = acc2[nt][r]; s += v; q += v * v; }
#pragma unroll
      for (int m = 1; m < 16; m <<= 1) { s += __shfl_xor(s, m); q += __shfl_xor(q, m); }
      const float mu = s * 0.0078125f;
      const float rstd = rsqrtf(q * 0.0078125f - mu * mu + 1e-5f);
      const int row = lg * 4 + r;
      const int nn = n0 + row;
      if (nn < NN) {
#pragma unroll
        for (int nt = 0; nt < 8; ++nt) {
          const int col = nt * 16 + lr;
          float v = (acc2[nt][r] - mu) * rstd * g2c[nt] + s2c[nt];
          v = silu_f(v);
          if (mode & 1) v += h0[(size_t)nn * 128 + col];
          if (mode & 2) {
            h[(size_t)nn * 128 + col] = v;          // final: pool input
          } else {
            hbf[(size_t)nn * 128 + col] = (__bf16)v;
            if (mode & 1) h0[(size_t)nn * 128 + col] = v;
          }
        }
      }
    }
  }
}

// ---------------------------------------------------------------------------
__global__ void pool_kernel(const float* __restrict__ h, const int* __restrict__ bid,
                            float* __restrict__ pooled) {
  const int d = threadIdx.x;
  const int n0 = blockIdx.x * 32;
  const int nend = (n0 + 32 < NN) ? (n0 + 32) : NN;
  float acc = 0.f;
  int cur = bid[n0];
  for (int n = n0; n < nend; ++n) {
    const int b = bid[n];
    if (b != cur) { atomicAdd(&pooled[cur * 128 + d], acc); acc = 0.f; cur = b; }
    acc += h[(size_t)n * 128 + d];
  }
  atomicAdd(&pooled[cur * 128 + d], acc);
}

__global__ void head_kernel(const float* __restrict__ pooled,
                            const float* __restrict__ W1, const float* __restrict__ b1,
                            const float* __restrict__ W2, const float* __restrict__ b2,
                            float* __restrict__ out) {
  __shared__ float buf[2];
  const int b = blockIdx.x, t = threadIdx.x;
  float s = b1[t];
  for (int k = 0; k < 128; ++k) s += pooled[b * 128 + k] * W1[k * 128 + t];
  s = fmaxf(s, 0.f) * W2[t];
#pragma unroll
  for (int m = 32; m >= 1; m >>= 1) s += __shfl_down(s, m);
  if ((t & 63) == 0) buf[t >> 6] = s;
  __syncthreads();
  if (t == 0) out[b] = buf[0] + buf[1] + b2[0];
}

// ---------------------------------------------------------------------------
extern "C" void kernel_launch(void* const* d_in, const int* in_sizes, int n_in,
                              void* d_out, int out_size, void* d_ws, size_t ws_size,
                              hipStream_t stream) {
  const float* x   = (const float*)d_in[0];
  const float* pos = (const float*)d_in[1];
  const int* eis[4] = {(const int*)d_in[2], (const int*)d_in[3],
                       (const int*)d_in[4], (const int*)d_in[5]};
  const int* bid = (const int*)d_in[6];
  const float* embW = (const float*)d_in[7];
  const float* embB = (const float*)d_in[8];
  const float* Wm1 = (const float*)d_in[9];
  const float* bm1 = (const float*)d_in[10];
  const float* gm1 = (const float*)d_in[11];
  const float* sm1 = (const float*)d_in[12];
  const float* Wm2 = (const float*)d_in[13];
  const float* bm2 = (const float*)d_in[14];
  const float* gm2 = (const float*)d_in[15];
  const float* sm2 = (const float*)d_in[16];
  const float* Wu1 = (const float*)d_in[17];
  const float* bu1 = (const float*)d_in[18];
  const float* gu1 = (const float*)d_in[19];
  const float* su1 = (const float*)d_in[20];
  const float* Wu2 = (const float*)d_in[21];
  const float* bu2 = (const float*)d_in[22];
  const float* gu2 = (const float*)d_in[23];
  const float* su2 = (const float*)d_in[24];
  const float* pW1 = (const float*)d_in[25];
  const float* pb1 = (const float*)d_in[26];
  const float* pW2 = (const float*)d_in[27];
  const float* pb2 = (const float*)d_in[28];
  float* out = (float*)d_out;

  char* wp = (char*)d_ws;
  float* h = (float*)wp;      wp += (size_t)NN * 128 * 4;
  float* h0 = (float*)wp;     wp += (size_t)NN * 128 * 4;
  float* pooled = (float*)wp; wp += 16 * 128 * 4;
  __bf16* aggb = (__bf16*)wp; wp += (size_t)NN * 128 * 2;
  __bf16* hbf = (__bf16*)wp;  wp += (size_t)NN * 128 * 2;
  __bf16* pq = (__bf16*)wp;   wp += (size_t)NN * 256 * 2;
  __bf16* msg = (__bf16*)wp;  wp += (size_t)NE * 128 * 2;
  __bf16* pqw = (__bf16*)wp;  wp += (size_t)NL * 32768 * 2;
  __bf16* w2p = (__bf16*)wp;  wp += (size_t)NL * 16384 * 2;
  __bf16* wu1p = (__bf16*)wp; wp += (size_t)NL * 32768 * 2;
  __bf16* wu2p = (__bf16*)wp; wp += (size_t)NL * 16384 * 2;
  int* deg = (int*)wp;        wp += (size_t)4 * NN * 4;
  int* cursor = (int*)wp;     wp += (size_t)4 * NN * 4;
  int* rowstart = (int*)wp;   wp += (size_t)4 * NN * 4;
  int* eord = (int*)wp;       wp += (size_t)4 * NE * 4;

  static int lds_attr_set = 0;
  if (!lds_attr_set) {
    hipFuncSetAttribute((const void*)edge_msg_kernel,
                        hipFuncAttributeMaxDynamicSharedMemorySize, 65536);
    lds_attr_set = 1;
  }

  pack_w1pq<<<320, 256, 0, stream>>>(Wm1, pqw);
  pack_weights<<<160, 256, 0, stream>>>(Wm2, w2p, 128, 128 * 128, NL * 4 * 8 * 64);
  pack_weights<<<320, 256, 0, stream>>>(Wu1, wu1p, 256, 256 * 128, NL * 8 * 8 * 64);
  pack_weights<<<160, 256, 0, stream>>>(Wu2, wu2p, 128, 128 * 128, NL * 4 * 8 * 64);

  hipMemsetAsync(deg, 0, (size_t)8 * NN * 4, stream);
  embed_kernel<<<(NN * 128) / 256, 256, 0, stream>>>(x, embW, embB, h0, hbf);
  for (int r = 0; r < 4; ++r)
    hist_kernel<<<NE / 256, 256, 0, stream>>>(eis[r], deg + (size_t)r * NN);
  scan_kernel<<<4, 1024, 0, stream>>>(deg, rowstart);
  for (int r = 0; r < 4; ++r)
    fill_kernel<<<NE / 256, 256, 0, stream>>>(eis[r], rowstart + (size_t)r * NN,
                                              cursor + (size_t)r * NN, eord + (size_t)r * NE);

  for (int layer = 0; layer < 5; ++layer) {
    for (int r = 0; r < 4; ++r) {
      const int i = layer * 4 + r;
      const int mode = (r == 3) ? ((layer == 4) ? 3 : 1) : 0;
      pq_kernel<<<625, 256, 0, stream>>>(hbf, pqw + (size_t)i * 32768, pq);
      edge_msg_kernel<<<NE / 256, 1024, 65536, stream>>>(
          pq, pos, eis[r], msg,
          w2p + (size_t)i * 16384,
          Wm1 + (size_t)i * 257 * 128 + 256 * 128,
          bm1 + i * 128, gm1 + i * 128, sm1 + i * 128,
          bm2 + i * 128, gm2 + i * 128, sm2 + i * 128);
      gather_kernel<<<(NN * 64) / 256, 256, 0, stream>>>(
          msg, rowstart + (size_t)r * NN, deg + (size_t)r * NN, eord + (size_t)r * NE, aggb);
      update_kernel<<<(NN + 63) / 64, 256, 0, stream>>>(
          h, aggb, hbf, h0, mode,
          wu1p + (size_t)i * 32768, wu2p + (size_t)i * 16384,
          bu1 + i * 128, gu1 + i * 128, su1 + i * 128,
          bu2 + i * 128, gu2 + i * 128, su2 + i * 128);
    }
  }

  hipMemsetAsync(pooled, 0, 16 * 128 * 4, stream);
  pool_kernel<<<(NN + 31) / 32, 128, 0, stream>>>(h, bid, pooled);
  head_kernel<<<16, 128, 0, stream>>>(pooled, pW1, pb1, pW2, pb2, out);
}

// Round 10
// 1736.790 us; speedup vs baseline: 4.4415x; 1.0941x over previous
//
#include <hip/hip_runtime.h>

#define NN 20000      // nodes
#define NE 160000     // edges per edge set
#define NL 20         // EGNN layer calls (4*DEPTH)

typedef float f32x4 __attribute__((ext_vector_type(4)));
typedef float f32x2 __attribute__((ext_vector_type(2)));
typedef __bf16 bf16x8 __attribute__((ext_vector_type(8)));
typedef __bf16 bf16x4 __attribute__((ext_vector_type(4)));

__device__ __forceinline__ float silu_f(float v) {
  return v * __builtin_amdgcn_rcpf(1.f + __expf(-v));
}

// ---------------------------------------------------------------------------
// Pack fp32 weight matrix [L][K][128] into MFMA-fragment order:
// out[((layer*ktn + kt)*8 + nt)*64 + lane][8], elem j = W[kt*32+(lane>>4)*8+j][nt*16+(lane&15)]
// ---------------------------------------------------------------------------
__global__ void pack_weights(const float* __restrict__ W, __bf16* __restrict__ out,
                             const int K, const int lstride, const int total) {
  const int idx = blockIdx.x * 256 + threadIdx.x;
  if (idx >= total) return;
  const int lane = idx & 63;
  const int nt = (idx >> 6) & 7;
  const int ktn = K >> 5;
  const int kt = (idx >> 9) % ktn;
  const int layer = (idx >> 9) / ktn;
  const int col = nt * 16 + (lane & 15);
  const int kb = kt * 32 + (lane >> 4) * 8;
  const float* src = W + (size_t)layer * lstride;
  __bf16* o = out + (size_t)idx * 8;
#pragma unroll
  for (int j = 0; j < 8; ++j) o[j] = (__bf16)src[(kb + j) * 128 + col];
}

// ---------------------------------------------------------------------------
// Pack Wm1 for the P/Q precompute (K=128, C=256).
// ---------------------------------------------------------------------------
__global__ void pack_w1pq(const float* __restrict__ Wm1, __bf16* __restrict__ out) {
  const int idx = blockIdx.x * 256 + threadIdx.x;   // total = NL*4*16*64 = 81920
  const int lane = idx & 63;
  const int nt = (idx >> 6) & 15;
  const int kt = (idx >> 10) & 3;
  const int layer = idx >> 12;
  const int c = nt * 16 + (lane & 15);
  const int kb = kt * 32 + (lane >> 4) * 8;
  const float* src = Wm1 + (size_t)layer * 257 * 128;
  __bf16* o = out + (size_t)idx * 8;
#pragma unroll
  for (int j = 0; j < 8; ++j) {
    const int k = kb + j;
    o[j] = (__bf16)((c < 128) ? src[k * 128 + c] : src[(128 + k) * 128 + (c - 128)]);
  }
}

// ---------------------------------------------------------------------------
__global__ void embed_kernel(const float* __restrict__ x, const float* __restrict__ embW,
                             const float* __restrict__ embB,
                             float* __restrict__ h0, __bf16* __restrict__ hbf) {
  const int idx = blockIdx.x * 256 + threadIdx.x;
  const int n = idx >> 7, d = idx & 127;
  const float v = x[n] * embW[d] + embB[d];
  h0[idx] = v;
  hbf[idx] = (__bf16)v;
}

// ---------------------------------------------------------------------------
// CSR build.
// ---------------------------------------------------------------------------
__global__ void hist_kernel(const int* __restrict__ ei, int* __restrict__ deg) {
  const int e = blockIdx.x * 256 + threadIdx.x;
  atomicAdd(&deg[ei[NE + e]], 1);
}

__global__ void scan_kernel(const int* __restrict__ deg, int* __restrict__ rowstart) {
  __shared__ int part[1024];
  const int r = blockIdx.x, t = threadIdx.x;
  const int* d = deg + (size_t)r * NN;
  int* rs = rowstart + (size_t)r * NN;
  int loc[20];
  int cnt = 0;
#pragma unroll
  for (int j = 0; j < 20; ++j) {
    const int i = t * 20 + j;
    const int v = (i < NN) ? d[i] : 0;
    loc[j] = cnt; cnt += v;
  }
  part[t] = cnt;
  __syncthreads();
  for (int off = 1; off < 1024; off <<= 1) {
    const int v = (t >= off) ? part[t - off] : 0;
    __syncthreads();
    part[t] += v;
    __syncthreads();
  }
  const int excl = (t == 0) ? 0 : part[t - 1];
#pragma unroll
  for (int j = 0; j < 20; ++j) {
    const int i = t * 20 + j;
    if (i < NN) rs[i] = excl + loc[j];
  }
}

__global__ void fill_kernel(const int* __restrict__ ei, const int* __restrict__ rowstart,
                            int* __restrict__ cursor, int* __restrict__ eord) {
  const int e = blockIdx.x * 256 + threadIdx.x;
  const int d = ei[NE + e];
  const int p = atomicAdd(&cursor[d], 1);
  eord[rowstart[d] + p] = e;
}

// ---------------------------------------------------------------------------
// P/Q precompute.
// ---------------------------------------------------------------------------
__global__ __launch_bounds__(256) void pq_kernel(
    const __bf16* __restrict__ hbf, const __bf16* __restrict__ pqw,
    __bf16* __restrict__ pq) {
  __shared__ __bf16 T1s[4][2048];
  const int t = threadIdx.x, w = t >> 6, l = t & 63;
  const int lr = l & 15, lg = l >> 4;
  const int wid = blockIdx.x * 4 + w;
  const int n0 = (wid >> 1) * 16;
  const int half = wid & 1;
  char* T1 = (char*)T1s[w];

  const int node = n0 + lr;
  bf16x8 bq[4];
#pragma unroll
  for (int kt = 0; kt < 4; ++kt)
    bq[kt] = *(const bf16x8*)(hbf + (size_t)node * 128 + kt * 32 + lg * 8);

  f32x4 acc[8];
#pragma unroll
  for (int nt = 0; nt < 8; ++nt) acc[nt] = (f32x4)0.f;
#pragma unroll
  for (int kt = 0; kt < 4; ++kt) {
#pragma unroll
    for (int nt = 0; nt < 8; ++nt) {
      const bf16x8 a = *(const bf16x8*)(pqw + ((size_t)((kt * 16 + half * 8 + nt) * 64 + l)) * 8);
      acc[nt] = __builtin_amdgcn_mfma_f32_16x16x32_bf16(a, bq[kt], acc[nt], 0, 0, 0);
    }
  }
#pragma unroll
  for (int nt = 0; nt < 8; ++nt) {
    bf16x4 v;
#pragma unroll
    for (int r = 0; r < 4; ++r) v[r] = (__bf16)acc[nt][r];
    *(bf16x4*)(T1 + ((lr * 256 + nt * 32 + lg * 8) ^ ((lr & 7) << 4))) = v;
  }
#pragma unroll
  for (int j = 0; j < 4; ++j) {
    const int row = j * 4 + lg;
    const uint4 v = *(const uint4*)(T1 + ((row * 256 + lr * 16) ^ ((row & 7) << 4)));
    *(uint4*)(pq + (size_t)(n0 + row) * 256 + half * 128 + lr * 8) = v;
  }
}

// ---------------------------------------------------------------------------
// Edge-message kernel: 512-thread blocks (8 waves), 48KB LDS -> 3 blocks/CU
// (24 waves/CU, 6 waves/SIMD). Each wave owns 16 edges; same R9 body.
// ---------------------------------------------------------------------------
__global__ __launch_bounds__(512, 6) void edge_msg_kernel(
    const __bf16* __restrict__ pq, const float* __restrict__ pos,
    const int* __restrict__ ei, __bf16* __restrict__ msg,
    const __bf16* __restrict__ w2p, const float* __restrict__ w1last,
    const float* __restrict__ bm1, const float* __restrict__ gm1, const float* __restrict__ sm1,
    const float* __restrict__ bm2, const float* __restrict__ gm2, const float* __restrict__ sm2) {
  extern __shared__ char lds[];
  {
    const int t = threadIdx.x;
    uint4* d = (uint4*)lds;
    const uint4* s2 = (const uint4*)w2p;
#pragma unroll
    for (int j = 0; j < 4; ++j) d[t + j * 512] = s2[t + j * 512];
  }
  __syncthreads();

  const int t = threadIdx.x, w = t >> 6, l = t & 63;
  const int lr = l & 15, lg = l >> 4;
  char* W2L = lds;                        // 32 KB
  char* T1  = lds + 32768 + w * 2048;     // 2 KB per wave (8 waves -> 16 KB)

  const int e0 = blockIdx.x * 128 + w * 16;
  const int es = ei[e0 + lr], ed = ei[NE + e0 + lr];
  const float dx = pos[ed * 3 + 0] - pos[es * 3 + 0];
  const float dy = pos[ed * 3 + 1] - pos[es * 3 + 1];
  const float dz = pos[ed * 3 + 2] - pos[es * 3 + 2];
  const float dist = sqrtf(dx * dx + dy * dy + dz * dz);

  // m1: lane holds dims d = kt*32 + lg*8 + j (fragment-ready)
  float v[4][8];
#pragma unroll
  for (int kt = 0; kt < 4; ++kt) {
    const int d0 = kt * 32 + lg * 8;
    const bf16x8 pA = *(const bf16x8*)(pq + (size_t)ed * 256 + d0);
    const bf16x8 qA = *(const bf16x8*)(pq + (size_t)es * 256 + 128 + d0);
    const f32x4 wl0 = *(const f32x4*)(w1last + d0), wl1 = *(const f32x4*)(w1last + d0 + 4);
    const f32x4 bb0 = *(const f32x4*)(bm1 + d0),    bb1 = *(const f32x4*)(bm1 + d0 + 4);
#pragma unroll
    for (int j = 0; j < 4; ++j) {
      v[kt][j]     = (float)pA[j]     + (float)qA[j]     + dist * wl0[j] + bb0[j];
      v[kt][j + 4] = (float)pA[j + 4] + (float)qA[j + 4] + dist * wl1[j] + bb1[j];
    }
  }
  // LN1 (row = edge lr; partners lane^16, lane^32)
  float s = 0.f, q = 0.f;
#pragma unroll
  for (int kt = 0; kt < 4; ++kt)
#pragma unroll
    for (int j = 0; j < 8; ++j) { const float x = v[kt][j]; s += x; q += x * x; }
  s += __shfl_xor(s, 16); q += __shfl_xor(q, 16);
  s += __shfl_xor(s, 32); q += __shfl_xor(q, 32);
  const float mu1 = s * 0.0078125f;
  const float rstd1 = rsqrtf(q * 0.0078125f - mu1 * mu1 + 1e-5f);
  bf16x8 bfrag[4];
#pragma unroll
  for (int kt = 0; kt < 4; ++kt) {
    const int d0 = kt * 32 + lg * 8;
    const f32x4 g0 = *(const f32x4*)(gm1 + d0), g1 = *(const f32x4*)(gm1 + d0 + 4);
    const f32x4 s0 = *(const f32x4*)(sm1 + d0), s1 = *(const f32x4*)(sm1 + d0 + 4);
    bf16x8 bf;
#pragma unroll
    for (int j = 0; j < 4; ++j) {
      bf[j]     = (__bf16)silu_f((v[kt][j]     - mu1) * rstd1 * g0[j] + s0[j]);
      bf[j + 4] = (__bf16)silu_f((v[kt][j + 4] - mu1) * rstd1 * g1[j] + s1[j]);
    }
    bfrag[kt] = bf;
  }
  // GEMM2 transposed: D[d2 = nt*16+lg*4+r][edge = lr]
  f32x4 acc2[8];
#pragma unroll
  for (int nt = 0; nt < 8; ++nt)
    acc2[nt] = *(const f32x4*)(bm2 + nt * 16 + lg * 4);
#pragma unroll
  for (int kt = 0; kt < 4; ++kt) {
#pragma unroll
    for (int nt = 0; nt < 8; ++nt) {
      const bf16x8 a = *(const bf16x8*)(W2L + ((kt * 8 + nt) * 64 + l) * 16);
      acc2[nt] = __builtin_amdgcn_mfma_f32_16x16x32_bf16(a, bfrag[kt], acc2[nt], 0, 0, 0);
    }
  }
  // LN2
  float s2 = 0.f, q2 = 0.f;
#pragma unroll
  for (int nt = 0; nt < 8; ++nt)
#pragma unroll
    for (int r = 0; r < 4; ++r) { const float x = acc2[nt][r]; s2 += x; q2 += x * x; }
  s2 += __shfl_xor(s2, 16); q2 += __shfl_xor(q2, 16);
  s2 += __shfl_xor(s2, 32); q2 += __shfl_xor(q2, 32);
  const float mu2 = s2 * 0.0078125f;
  const float rstd2 = rsqrtf(q2 * 0.0078125f - mu2 * mu2 + 1e-5f);
  // SiLU -> msg via two 64-dim passes through the 2KB T1
#pragma unroll
  for (int hh = 0; hh < 2; ++hh) {
#pragma unroll
    for (int nt4 = 0; nt4 < 4; ++nt4) {
      const int nt = hh * 4 + nt4;
      const f32x4 g2 = *(const f32x4*)(gm2 + nt * 16 + lg * 4);
      const f32x4 b2 = *(const f32x4*)(sm2 + nt * 16 + lg * 4);
      bf16x4 pk;
#pragma unroll
      for (int r = 0; r < 4; ++r)
        pk[r] = (__bf16)silu_f((acc2[nt][r] - mu2) * rstd2 * g2[r] + b2[r]);
      *(bf16x4*)(T1 + ((lr * 128 + nt4 * 32 + lg * 8) ^ ((lr & 7) << 4))) = pk;
    }
    // store this 64-dim half: 16 edges x 128B (one full cache line each)
#pragma unroll
    for (int j = 0; j < 2; ++j) {
      const int e8 = j * 8 + (l >> 3);
      const uint4 val = *(const uint4*)(T1 + ((e8 * 128 + (l & 7) * 16) ^ ((e8 & 7) << 4)));
      *(uint4*)((char*)msg + (size_t)(e0 + e8) * 256 + hh * 128 + (l & 7) * 16) = val;
    }
  }
}

// ---------------------------------------------------------------------------
// CSR gather at full occupancy -> bf16 agg.
// ---------------------------------------------------------------------------
__global__ void gather_kernel(const __bf16* __restrict__ msg,
                              const int* __restrict__ rowstart, const int* __restrict__ deg,
                              const int* __restrict__ eord, __bf16* __restrict__ aggb) {
  const int t = blockIdx.x * 256 + threadIdx.x;
  const int n = t >> 6, pd = t & 63;
  const int s = rowstart[n], dg = deg[n];
  float a0 = 0.f, a1 = 0.f;
  int i = 0;
  for (; i + 2 <= dg; i += 2) {
    const unsigned v0 = *(const unsigned*)(msg + (size_t)eord[s + i] * 128 + pd * 2);
    const unsigned v1 = *(const unsigned*)(msg + (size_t)eord[s + i + 1] * 128 + pd * 2);
    a0 += __uint_as_float(v0 << 16) + __uint_as_float(v1 << 16);
    a1 += __uint_as_float(v0 & 0xFFFF0000u) + __uint_as_float(v1 & 0xFFFF0000u);
  }
  if (i < dg) {
    const unsigned v0 = *(const unsigned*)(msg + (size_t)eord[s + i] * 128 + pd * 2);
    a0 += __uint_as_float(v0 << 16);
    a1 += __uint_as_float(v0 & 0xFFFF0000u);
  }
  __bf16 o0 = (__bf16)a0, o1 = (__bf16)a1;
  unsigned pk = ((unsigned)*(unsigned short*)&o0) | (((unsigned)*(unsigned short*)&o1) << 16);
  *(unsigned*)(aggb + (size_t)n * 128 + pd * 2) = pk;
}

// ---------------------------------------------------------------------------
// Node-update MLP. mode: bit0 = residual (+h0, update h0), bit1 = final
// (write h fp32 for pool; skip hbf/h0).
// ---------------------------------------------------------------------------
__global__ __launch_bounds__(256) void update_kernel(
    float* __restrict__ h, const __bf16* __restrict__ aggb, __bf16* __restrict__ hbf,
    float* __restrict__ h0, const int mode,
    const __bf16* __restrict__ w1p, const __bf16* __restrict__ w2p,
    const float* __restrict__ bu1, const float* __restrict__ gu1, const float* __restrict__ su1,
    const float* __restrict__ bu2, const float* __restrict__ gu2, const float* __restrict__ su2) {
  __shared__ __bf16 T1s[4][16 * 128];
  const int t = threadIdx.x, w = t >> 6, l = t & 63;
  const int lr = l & 15, lg = l >> 4;
  char* T1 = (char*)T1s[w];
  const int n0 = blockIdx.x * 64 + w * 16;
  const int n = n0 + lr;
  const int valid = (n < NN);
  const int nc = valid ? n : 0;

  bf16x8 ah[4], af[4];
#pragma unroll
  for (int kt = 0; kt < 4; ++kt) {
    ah[kt] = *(const bf16x8*)(hbf + (size_t)nc * 128 + kt * 32 + lg * 8);
    af[kt] = *(const bf16x8*)(aggb + (size_t)nc * 128 + kt * 32 + lg * 8);
  }
  f32x4 acc[8];
#pragma unroll
  for (int nt = 0; nt < 8; ++nt) {
    const float bb = bu1[nt * 16 + lr];
#pragma unroll
    for (int r = 0; r < 4; ++r) acc[nt][r] = bb;
  }
#pragma unroll
  for (int kt = 0; kt < 8; ++kt) {
    const bf16x8 a = (kt < 4) ? ah[kt] : af[kt - 4];
#pragma unroll
    for (int nt = 0; nt < 8; ++nt) {
      const bf16x8 b = *(const bf16x8*)(w1p + ((size_t)((kt * 8 + nt) * 64 + l)) * 8);
      acc[nt] = __builtin_amdgcn_mfma_f32_16x16x32_bf16(a, b, acc[nt], 0, 0, 0);
    }
  }
  {
    float g1c[8], s1c[8];
#pragma unroll
    for (int nt = 0; nt < 8; ++nt) { g1c[nt] = gu1[nt * 16 + lr]; s1c[nt] = su1[nt * 16 + lr]; }
#pragma unroll
    for (int r = 0; r < 4; ++r) {
      float s = 0.f, q = 0.f;
#pragma unroll
      for (int nt = 0; nt < 8; ++nt) { const float v = acc[nt][r]; s += v; q += v * v; }
#pragma unroll
      for (int m = 1; m < 16; m <<= 1) { s += __shfl_xor(s, m); q += __shfl_xor(q, m); }
      const float mu = s * 0.0078125f;
      const float rstd = rsqrtf(q * 0.0078125f - mu * mu + 1e-5f);
      const int row = lg * 4 + r;
#pragma unroll
      for (int nt = 0; nt < 8; ++nt) {
        float v = (acc[nt][r] - mu) * rstd * g1c[nt] + s1c[nt];
        v = silu_f(v);
        const int col = nt * 16 + lr;
        *(__bf16*)(T1 + ((row * 256 + col * 2) ^ ((row & 7) << 4))) = (__bf16)v;
      }
    }
  }
  f32x4 acc2[8];
#pragma unroll
  for (int nt = 0; nt < 8; ++nt) {
    const float bb = bu2[nt * 16 + lr];
#pragma unroll
    for (int r = 0; r < 4; ++r) acc2[nt][r] = bb;
  }
#pragma unroll
  for (int kt = 0; kt < 4; ++kt) {
    const bf16x8 a = *(const bf16x8*)(T1 + ((lr * 256 + kt * 64 + lg * 16) ^ ((lr & 7) << 4)));
#pragma unroll
    for (int nt = 0; nt < 8; ++nt) {
      const bf16x8 b = *(const bf16x8*)(w2p + ((size_t)((kt * 8 + nt) * 64 + l)) * 8);
      acc2[nt] = __builtin_amdgcn_mfma_f32_16x16x32_bf16(a, b, acc2[nt], 0, 0, 0);
    }
  }
  {
    float g2c[8], s2c[8];
#pragma unroll
    for (int nt = 0; nt < 8; ++nt) { g2c[nt] = gu2[nt * 16 + lr]; s2c[nt] = su2[nt * 16 + lr]; }
#pragma unroll
    for (int r = 0; r < 4; ++r) {
      float s = 0.f, q = 0.f;
#pragma unroll
      for (int nt = 0; nt < 8; ++nt) { const float v = acc2[nt][r]; s += v; q += v * v; }
#pragma unroll
      for (int m = 1; m < 16; m <<= 1) { s += __shfl_xor(s, m); q += __shfl_xor(q, m); }
      const float mu = s * 0.0078125f;
      const float rstd = rsqrtf(q * 0.0078125f - mu * mu + 1e-5f);
      const int row = lg * 4 + r;
      const int nn = n0 + row;
      if (nn < NN) {
#pragma unroll
        for (int nt = 0; nt < 8; ++nt) {
          const int col = nt * 16 + lr;
          float v = (acc2[nt][r] - mu) * rstd * g2c[nt] + s2c[nt];
          v = silu_f(v);
          if (mode & 1) v += h0[(size_t)nn * 128 + col];
          if (mode & 2) {
            h[(size_t)nn * 128 + col] = v;          // final: pool input
          } else {
            hbf[(size_t)nn * 128 + col] = (__bf16)v;
            if (mode & 1) h0[(size_t)nn * 128 + col] = v;
          }
        }
      }
    }
  }
}

// ---------------------------------------------------------------------------
__global__ void pool_kernel(const float* __restrict__ h, const int* __restrict__ bid,
                            float* __restrict__ pooled) {
  const int d = threadIdx.x;
  const int n0 = blockIdx.x * 32;
  const int nend = (n0 + 32 < NN) ? (n0 + 32) : NN;
  float acc = 0.f;
  int cur = bid[n0];
  for (int n = n0; n < nend; ++n) {
    const int b = bid[n];
    if (b != cur) { atomicAdd(&pooled[cur * 128 + d], acc); acc = 0.f; cur = b; }
    acc += h[(size_t)n * 128 + d];
  }
  atomicAdd(&pooled[cur * 128 + d], acc);
}

__global__ void head_kernel(const float* __restrict__ pooled,
                            const float* __restrict__ W1, const float* __restrict__ b1,
                            const float* __restrict__ W2, const float* __restrict__ b2,
                            float* __restrict__ out) {
  __shared__ float buf[2];
  const int b = blockIdx.x, t = threadIdx.x;
  float s = b1[t];
  for (int k = 0; k < 128; ++k) s += pooled[b * 128 + k] * W1[k * 128 + t];
  s = fmaxf(s, 0.f) * W2[t];
#pragma unroll
  for (int m = 32; m >= 1; m >>= 1) s += __shfl_down(s, m);
  if ((t & 63) == 0) buf[t >> 6] = s;
  __syncthreads();
  if (t == 0) out[b] = buf[0] + buf[1] + b2[0];
}

// ---------------------------------------------------------------------------
extern "C" void kernel_launch(void* const* d_in, const int* in_sizes, int n_in,
                              void* d_out, int out_size, void* d_ws, size_t ws_size,
                              hipStream_t stream) {
  const float* x   = (const float*)d_in[0];
  const float* pos = (const float*)d_in[1];
  const int* eis[4] = {(const int*)d_in[2], (const int*)d_in[3],
                       (const int*)d_in[4], (const int*)d_in[5]};
  const int* bid = (const int*)d_in[6];
  const float* embW = (const float*)d_in[7];
  const float* embB = (const float*)d_in[8];
  const float* Wm1 = (const float*)d_in[9];
  const float* bm1 = (const float*)d_in[10];
  const float* gm1 = (const float*)d_in[11];
  const float* sm1 = (const float*)d_in[12];
  const float* Wm2 = (const float*)d_in[13];
  const float* bm2 = (const float*)d_in[14];
  const float* gm2 = (const float*)d_in[15];
  const float* sm2 = (const float*)d_in[16];
  const float* Wu1 = (const float*)d_in[17];
  const float* bu1 = (const float*)d_in[18];
  const float* gu1 = (const float*)d_in[19];
  const float* su1 = (const float*)d_in[20];
  const float* Wu2 = (const float*)d_in[21];
  const float* bu2 = (const float*)d_in[22];
  const float* gu2 = (const float*)d_in[23];
  const float* su2 = (const float*)d_in[24];
  const float* pW1 = (const float*)d_in[25];
  const float* pb1 = (const float*)d_in[26];
  const float* pW2 = (const float*)d_in[27];
  const float* pb2 = (const float*)d_in[28];
  float* out = (float*)d_out;

  char* wp = (char*)d_ws;
  float* h = (float*)wp;      wp += (size_t)NN * 128 * 4;
  float* h0 = (float*)wp;     wp += (size_t)NN * 128 * 4;
  float* pooled = (float*)wp; wp += 16 * 128 * 4;
  __bf16* aggb = (__bf16*)wp; wp += (size_t)NN * 128 * 2;
  __bf16* hbf = (__bf16*)wp;  wp += (size_t)NN * 128 * 2;
  __bf16* pq = (__bf16*)wp;   wp += (size_t)NN * 256 * 2;
  __bf16* msg = (__bf16*)wp;  wp += (size_t)NE * 128 * 2;
  __bf16* pqw = (__bf16*)wp;  wp += (size_t)NL * 32768 * 2;
  __bf16* w2p = (__bf16*)wp;  wp += (size_t)NL * 16384 * 2;
  __bf16* wu1p = (__bf16*)wp; wp += (size_t)NL * 32768 * 2;
  __bf16* wu2p = (__bf16*)wp; wp += (size_t)NL * 16384 * 2;
  int* deg = (int*)wp;        wp += (size_t)4 * NN * 4;
  int* cursor = (int*)wp;     wp += (size_t)4 * NN * 4;
  int* rowstart = (int*)wp;   wp += (size_t)4 * NN * 4;
  int* eord = (int*)wp;       wp += (size_t)4 * NE * 4;

  static int lds_attr_set = 0;
  if (!lds_attr_set) {
    hipFuncSetAttribute((const void*)edge_msg_kernel,
                        hipFuncAttributeMaxDynamicSharedMemorySize, 49152);
    lds_attr_set = 1;
  }

  pack_w1pq<<<320, 256, 0, stream>>>(Wm1, pqw);
  pack_weights<<<160, 256, 0, stream>>>(Wm2, w2p, 128, 128 * 128, NL * 4 * 8 * 64);
  pack_weights<<<320, 256, 0, stream>>>(Wu1, wu1p, 256, 256 * 128, NL * 8 * 8 * 64);
  pack_weights<<<160, 256, 0, stream>>>(Wu2, wu2p, 128, 128 * 128, NL * 4 * 8 * 64);

  hipMemsetAsync(deg, 0, (size_t)8 * NN * 4, stream);
  embed_kernel<<<(NN * 128) / 256, 256, 0, stream>>>(x, embW, embB, h0, hbf);
  for (int r = 0; r < 4; ++r)
    hist_kernel<<<NE / 256, 256, 0, stream>>>(eis[r], deg + (size_t)r * NN);
  scan_kernel<<<4, 1024, 0, stream>>>(deg, rowstart);
  for (int r = 0; r < 4; ++r)
    fill_kernel<<<NE / 256, 256, 0, stream>>>(eis[r], rowstart + (size_t)r * NN,
                                              cursor + (size_t)r * NN, eord + (size_t)r * NE);

  for (int layer = 0; layer < 5; ++layer) {
    for (int r = 0; r < 4; ++r) {
      const int i = layer * 4 + r;
      const int mode = (r == 3) ? ((layer == 4) ? 3 : 1) : 0;
      pq_kernel<<<625, 256, 0, stream>>>(hbf, pqw + (size_t)i * 32768, pq);
      edge_msg_kernel<<<NE / 128, 512, 49152, stream>>>(
          pq, pos, eis[r], msg,
          w2p + (size_t)i * 16384,
          Wm1 + (size_t)i * 257 * 128 + 256 * 128,
          bm1 + i * 128, gm1 + i * 128, sm1 + i * 128,
          bm2 + i * 128, gm2 + i * 128, sm2 + i * 128);
      gather_kernel<<<(NN * 64) / 256, 256, 0, stream>>>(
          msg, rowstart + (size_t)r * NN, deg + (size_t)r * NN, eord + (size_t)r * NE, aggb);
      update_kernel<<<(NN + 63) / 64, 256, 0, stream>>>(
          h, aggb, hbf, h0, mode,
          wu1p + (size_t)i * 32768, wu2p + (size_t)i * 16384,
          bu1 + i * 128, gu1 + i * 128, su1 + i * 128,
          bu2 + i * 128, gu2 + i * 128, su2 + i * 128);
    }
  }

  hipMemsetAsync(pooled, 0, 16 * 128 * 4, stream);
  pool_kernel<<<(NN + 31) / 32, 128, 0, stream>>>(h, bid, pooled);
  head_kernel<<<16, 128, 0, stream>>>(pooled, pW1, pb1, pW2, pb2, out);
}

// Round 11
// 1567.886 us; speedup vs baseline: 4.9200x; 1.1077x over previous
//
#include <hip/hip_runtime.h>

#define NN 20000      // nodes
#define NE 160000     // edges per edge set
#define NL 20         // EGNN layer calls (4*DEPTH)

typedef float f32x4 __attribute__((ext_vector_type(4)));
typedef float f32x2 __attribute__((ext_vector_type(2)));
typedef __bf16 bf16x8 __attribute__((ext_vector_type(8)));
typedef __bf16 bf16x4 __attribute__((ext_vector_type(4)));

__device__ __forceinline__ float silu_f(float v) {
  return v * __builtin_amdgcn_rcpf(1.f + __expf(-v));
}

// ---------------------------------------------------------------------------
// Pack fp32 weight matrix [L][K][128] into MFMA-fragment order:
// out[((layer*ktn + kt)*8 + nt)*64 + lane][8], elem j = W[kt*32+(lane>>4)*8+j][nt*16+(lane&15)]
// ---------------------------------------------------------------------------
__global__ void pack_weights(const float* __restrict__ W, __bf16* __restrict__ out,
                             const int K, const int lstride, const int total) {
  const int idx = blockIdx.x * 256 + threadIdx.x;
  if (idx >= total) return;
  const int lane = idx & 63;
  const int nt = (idx >> 6) & 7;
  const int ktn = K >> 5;
  const int kt = (idx >> 9) % ktn;
  const int layer = (idx >> 9) / ktn;
  const int col = nt * 16 + (lane & 15);
  const int kb = kt * 32 + (lane >> 4) * 8;
  const float* src = W + (size_t)layer * lstride;
  __bf16* o = out + (size_t)idx * 8;
#pragma unroll
  for (int j = 0; j < 8; ++j) o[j] = (__bf16)src[(kb + j) * 128 + col];
}

// ---------------------------------------------------------------------------
// Pack Wm1 for the P/Q precompute (K=128, C=256).
// ---------------------------------------------------------------------------
__global__ void pack_w1pq(const float* __restrict__ Wm1, __bf16* __restrict__ out) {
  const int idx = blockIdx.x * 256 + threadIdx.x;   // total = NL*4*16*64 = 81920
  const int lane = idx & 63;
  const int nt = (idx >> 6) & 15;
  const int kt = (idx >> 10) & 3;
  const int layer = idx >> 12;
  const int c = nt * 16 + (lane & 15);
  const int kb = kt * 32 + (lane >> 4) * 8;
  const float* src = Wm1 + (size_t)layer * 257 * 128;
  __bf16* o = out + (size_t)idx * 8;
#pragma unroll
  for (int j = 0; j < 8; ++j) {
    const int k = kb + j;
    o[j] = (__bf16)((c < 128) ? src[k * 128 + c] : src[(128 + k) * 128 + (c - 128)]);
  }
}

// ---------------------------------------------------------------------------
__global__ void embed_kernel(const float* __restrict__ x, const float* __restrict__ embW,
                             const float* __restrict__ embB,
                             float* __restrict__ h0, __bf16* __restrict__ hbf) {
  const int idx = blockIdx.x * 256 + threadIdx.x;
  const int n = idx >> 7, d = idx & 127;
  const float v = x[n] * embW[d] + embB[d];
  h0[idx] = v;
  hbf[idx] = (__bf16)v;
}

// ---------------------------------------------------------------------------
// CSR build. fill emits per-slot (src,dst) so edges can be processed in CSR
// (dst-sorted) order: P[dst] gathers become sequential, msg stores contiguous.
// ---------------------------------------------------------------------------
__global__ void hist_kernel(const int* __restrict__ ei, int* __restrict__ deg) {
  const int e = blockIdx.x * 256 + threadIdx.x;
  atomicAdd(&deg[ei[NE + e]], 1);
}

__global__ void scan_kernel(const int* __restrict__ deg, int* __restrict__ rowstart) {
  __shared__ int part[1024];
  const int r = blockIdx.x, t = threadIdx.x;
  const int* d = deg + (size_t)r * NN;
  int* rs = rowstart + (size_t)r * NN;
  int loc[20];
  int cnt = 0;
#pragma unroll
  for (int j = 0; j < 20; ++j) {
    const int i = t * 20 + j;
    const int v = (i < NN) ? d[i] : 0;
    loc[j] = cnt; cnt += v;
  }
  part[t] = cnt;
  __syncthreads();
  for (int off = 1; off < 1024; off <<= 1) {
    const int v = (t >= off) ? part[t - off] : 0;
    __syncthreads();
    part[t] += v;
    __syncthreads();
  }
  const int excl = (t == 0) ? 0 : part[t - 1];
#pragma unroll
  for (int j = 0; j < 20; ++j) {
    const int i = t * 20 + j;
    if (i < NN) rs[i] = excl + loc[j];
  }
}

__global__ void fill_kernel(const int* __restrict__ ei, const int* __restrict__ rowstart,
                            int* __restrict__ cursor,
                            int* __restrict__ esrc, int* __restrict__ edst) {
  const int e = blockIdx.x * 256 + threadIdx.x;
  const int sN = ei[e];
  const int d = ei[NE + e];
  const int p = rowstart[d] + atomicAdd(&cursor[d], 1);
  esrc[p] = sN;
  edst[p] = d;
}

// ---------------------------------------------------------------------------
// P/Q precompute.
// ---------------------------------------------------------------------------
__global__ __launch_bounds__(256) void pq_kernel(
    const __bf16* __restrict__ hbf, const __bf16* __restrict__ pqw,
    __bf16* __restrict__ pq) {
  __shared__ __bf16 T1s[4][2048];
  const int t = threadIdx.x, w = t >> 6, l = t & 63;
  const int lr = l & 15, lg = l >> 4;
  const int wid = blockIdx.x * 4 + w;
  const int n0 = (wid >> 1) * 16;
  const int half = wid & 1;
  char* T1 = (char*)T1s[w];

  const int node = n0 + lr;
  bf16x8 bq[4];
#pragma unroll
  for (int kt = 0; kt < 4; ++kt)
    bq[kt] = *(const bf16x8*)(hbf + (size_t)node * 128 + kt * 32 + lg * 8);

  f32x4 acc[8];
#pragma unroll
  for (int nt = 0; nt < 8; ++nt) acc[nt] = (f32x4)0.f;
#pragma unroll
  for (int kt = 0; kt < 4; ++kt) {
#pragma unroll
    for (int nt = 0; nt < 8; ++nt) {
      const bf16x8 a = *(const bf16x8*)(pqw + ((size_t)((kt * 16 + half * 8 + nt) * 64 + l)) * 8);
      acc[nt] = __builtin_amdgcn_mfma_f32_16x16x32_bf16(a, bq[kt], acc[nt], 0, 0, 0);
    }
  }
#pragma unroll
  for (int nt = 0; nt < 8; ++nt) {
    bf16x4 v;
#pragma unroll
    for (int r = 0; r < 4; ++r) v[r] = (__bf16)acc[nt][r];
    *(bf16x4*)(T1 + ((lr * 256 + nt * 32 + lg * 8) ^ ((lr & 7) << 4))) = v;
  }
#pragma unroll
  for (int j = 0; j < 4; ++j) {
    const int row = j * 4 + lg;
    const uint4 v = *(const uint4*)(T1 + ((row * 256 + lr * 16) ^ ((row & 7) << 4)));
    *(uint4*)(pq + (size_t)(n0 + row) * 256 + half * 128 + lr * 8) = v;
  }
}

// ---------------------------------------------------------------------------
// Edge-message kernel: 512-thread blocks (8 waves), 48KB LDS, edges processed
// in CSR (dst-sorted) order via esrc/edst -> P[dst] gathers are sequential,
// msg stores contiguous in CSR slot order.
// ---------------------------------------------------------------------------
__global__ __launch_bounds__(512, 6) void edge_msg_kernel(
    const __bf16* __restrict__ pq, const float* __restrict__ pos,
    const int* __restrict__ esrc, const int* __restrict__ edst,
    __bf16* __restrict__ msg,
    const __bf16* __restrict__ w2p, const float* __restrict__ w1last,
    const float* __restrict__ bm1, const float* __restrict__ gm1, const float* __restrict__ sm1,
    const float* __restrict__ bm2, const float* __restrict__ gm2, const float* __restrict__ sm2) {
  extern __shared__ char lds[];
  {
    const int t = threadIdx.x;
    uint4* d = (uint4*)lds;
    const uint4* s2 = (const uint4*)w2p;
#pragma unroll
    for (int j = 0; j < 4; ++j) d[t + j * 512] = s2[t + j * 512];
  }
  __syncthreads();

  const int t = threadIdx.x, w = t >> 6, l = t & 63;
  const int lr = l & 15, lg = l >> 4;
  char* W2L = lds;                        // 32 KB
  char* T1  = lds + 32768 + w * 2048;     // 2 KB per wave

  const int e0 = blockIdx.x * 128 + w * 16;   // CSR slot base
  const int es = esrc[e0 + lr], ed = edst[e0 + lr];
  const float dx = pos[ed * 3 + 0] - pos[es * 3 + 0];
  const float dy = pos[ed * 3 + 1] - pos[es * 3 + 1];
  const float dz = pos[ed * 3 + 2] - pos[es * 3 + 2];
  const float dist = sqrtf(dx * dx + dy * dy + dz * dz);

  // m1: lane holds dims d = kt*32 + lg*8 + j (fragment-ready)
  float v[4][8];
#pragma unroll
  for (int kt = 0; kt < 4; ++kt) {
    const int d0 = kt * 32 + lg * 8;
    const bf16x8 pA = *(const bf16x8*)(pq + (size_t)ed * 256 + d0);
    const bf16x8 qA = *(const bf16x8*)(pq + (size_t)es * 256 + 128 + d0);
    const f32x4 wl0 = *(const f32x4*)(w1last + d0), wl1 = *(const f32x4*)(w1last + d0 + 4);
    const f32x4 bb0 = *(const f32x4*)(bm1 + d0),    bb1 = *(const f32x4*)(bm1 + d0 + 4);
#pragma unroll
    for (int j = 0; j < 4; ++j) {
      v[kt][j]     = (float)pA[j]     + (float)qA[j]     + dist * wl0[j] + bb0[j];
      v[kt][j + 4] = (float)pA[j + 4] + (float)qA[j + 4] + dist * wl1[j] + bb1[j];
    }
  }
  // LN1 (row = edge lr; partners lane^16, lane^32)
  float s = 0.f, q = 0.f;
#pragma unroll
  for (int kt = 0; kt < 4; ++kt)
#pragma unroll
    for (int j = 0; j < 8; ++j) { const float x = v[kt][j]; s += x; q += x * x; }
  s += __shfl_xor(s, 16); q += __shfl_xor(q, 16);
  s += __shfl_xor(s, 32); q += __shfl_xor(q, 32);
  const float mu1 = s * 0.0078125f;
  const float rstd1 = rsqrtf(q * 0.0078125f - mu1 * mu1 + 1e-5f);
  bf16x8 bfrag[4];
#pragma unroll
  for (int kt = 0; kt < 4; ++kt) {
    const int d0 = kt * 32 + lg * 8;
    const f32x4 g0 = *(const f32x4*)(gm1 + d0), g1 = *(const f32x4*)(gm1 + d0 + 4);
    const f32x4 s0 = *(const f32x4*)(sm1 + d0), s1 = *(const f32x4*)(sm1 + d0 + 4);
    bf16x8 bf;
#pragma unroll
    for (int j = 0; j < 4; ++j) {
      bf[j]     = (__bf16)silu_f((v[kt][j]     - mu1) * rstd1 * g0[j] + s0[j]);
      bf[j + 4] = (__bf16)silu_f((v[kt][j + 4] - mu1) * rstd1 * g1[j] + s1[j]);
    }
    bfrag[kt] = bf;
  }
  // GEMM2 transposed: D[d2 = nt*16+lg*4+r][edge = lr]
  f32x4 acc2[8];
#pragma unroll
  for (int nt = 0; nt < 8; ++nt)
    acc2[nt] = *(const f32x4*)(bm2 + nt * 16 + lg * 4);
#pragma unroll
  for (int kt = 0; kt < 4; ++kt) {
#pragma unroll
    for (int nt = 0; nt < 8; ++nt) {
      const bf16x8 a = *(const bf16x8*)(W2L + ((kt * 8 + nt) * 64 + l) * 16);
      acc2[nt] = __builtin_amdgcn_mfma_f32_16x16x32_bf16(a, bfrag[kt], acc2[nt], 0, 0, 0);
    }
  }
  // LN2
  float s2 = 0.f, q2 = 0.f;
#pragma unroll
  for (int nt = 0; nt < 8; ++nt)
#pragma unroll
    for (int r = 0; r < 4; ++r) { const float x = acc2[nt][r]; s2 += x; q2 += x * x; }
  s2 += __shfl_xor(s2, 16); q2 += __shfl_xor(q2, 16);
  s2 += __shfl_xor(s2, 32); q2 += __shfl_xor(q2, 32);
  const float mu2 = s2 * 0.0078125f;
  const float rstd2 = rsqrtf(q2 * 0.0078125f - mu2 * mu2 + 1e-5f);
  // SiLU -> msg via two 64-dim passes through the 2KB T1
#pragma unroll
  for (int hh = 0; hh < 2; ++hh) {
#pragma unroll
    for (int nt4 = 0; nt4 < 4; ++nt4) {
      const int nt = hh * 4 + nt4;
      const f32x4 g2 = *(const f32x4*)(gm2 + nt * 16 + lg * 4);
      const f32x4 b2 = *(const f32x4*)(sm2 + nt * 16 + lg * 4);
      bf16x4 pk;
#pragma unroll
      for (int r = 0; r < 4; ++r)
        pk[r] = (__bf16)silu_f((acc2[nt][r] - mu2) * rstd2 * g2[r] + b2[r]);
      *(bf16x4*)(T1 + ((lr * 128 + nt4 * 32 + lg * 8) ^ ((lr & 7) << 4))) = pk;
    }
#pragma unroll
    for (int j = 0; j < 2; ++j) {
      const int e8 = j * 8 + (l >> 3);
      const uint4 val = *(const uint4*)(T1 + ((e8 * 128 + (l & 7) * 16) ^ ((e8 & 7) << 4)));
      *(uint4*)((char*)msg + (size_t)(e0 + e8) * 256 + hh * 128 + (l & 7) * 16) = val;
    }
  }
}

// ---------------------------------------------------------------------------
// Aggregation: msg rows are ALREADY in CSR order -> contiguous streaming read
// of deg*256B per node, no indirection. -> bf16 agg.
// ---------------------------------------------------------------------------
__global__ void gather_kernel(const __bf16* __restrict__ msg,
                              const int* __restrict__ rowstart, const int* __restrict__ deg,
                              __bf16* __restrict__ aggb) {
  const int t = blockIdx.x * 256 + threadIdx.x;
  const int n = t >> 6, pd = t & 63;
  const int s = rowstart[n], dg = deg[n];
  const char* base = (const char*)msg + (size_t)s * 256 + pd * 4;
  float a0 = 0.f, a1 = 0.f;
  int i = 0;
  for (; i + 2 <= dg; i += 2) {
    const unsigned v0 = *(const unsigned*)(base + (size_t)i * 256);
    const unsigned v1 = *(const unsigned*)(base + (size_t)(i + 1) * 256);
    a0 += __uint_as_float(v0 << 16) + __uint_as_float(v1 << 16);
    a1 += __uint_as_float(v0 & 0xFFFF0000u) + __uint_as_float(v1 & 0xFFFF0000u);
  }
  if (i < dg) {
    const unsigned v0 = *(const unsigned*)(base + (size_t)i * 256);
    a0 += __uint_as_float(v0 << 16);
    a1 += __uint_as_float(v0 & 0xFFFF0000u);
  }
  __bf16 o0 = (__bf16)a0, o1 = (__bf16)a1;
  unsigned pk = ((unsigned)*(unsigned short*)&o0) | (((unsigned)*(unsigned short*)&o1) << 16);
  *(unsigned*)(aggb + (size_t)n * 128 + pd * 2) = pk;
}

// ---------------------------------------------------------------------------
// Node-update MLP. mode: bit0 = residual (+h0, update h0), bit1 = final
// (write h fp32 for pool; skip hbf/h0).
// ---------------------------------------------------------------------------
__global__ __launch_bounds__(256) void update_kernel(
    float* __restrict__ h, const __bf16* __restrict__ aggb, __bf16* __restrict__ hbf,
    float* __restrict__ h0, const int mode,
    const __bf16* __restrict__ w1p, const __bf16* __restrict__ w2p,
    const float* __restrict__ bu1, const float* __restrict__ gu1, const float* __restrict__ su1,
    const float* __restrict__ bu2, const float* __restrict__ gu2, const float* __restrict__ su2) {
  __shared__ __bf16 T1s[4][16 * 128];
  const int t = threadIdx.x, w = t >> 6, l = t & 63;
  const int lr = l & 15, lg = l >> 4;
  char* T1 = (char*)T1s[w];
  const int n0 = blockIdx.x * 64 + w * 16;
  const int n = n0 + lr;
  const int valid = (n < NN);
  const int nc = valid ? n : 0;

  bf16x8 ah[4], af[4];
#pragma unroll
  for (int kt = 0; kt < 4; ++kt) {
    ah[kt] = *(const bf16x8*)(hbf + (size_t)nc * 128 + kt * 32 + lg * 8);
    af[kt] = *(const bf16x8*)(aggb + (size_t)nc * 128 + kt * 32 + lg * 8);
  }
  f32x4 acc[8];
#pragma unroll
  for (int nt = 0; nt < 8; ++nt) {
    const float bb = bu1[nt * 16 + lr];
#pragma unroll
    for (int r = 0; r < 4; ++r) acc[nt][r] = bb;
  }
#pragma unroll
  for (int kt = 0; kt < 8; ++kt) {
    const bf16x8 a = (kt < 4) ? ah[kt] : af[kt - 4];
#pragma unroll
    for (int nt = 0; nt < 8; ++nt) {
      const bf16x8 b = *(const bf16x8*)(w1p + ((size_t)((kt * 8 + nt) * 64 + l)) * 8);
      acc[nt] = __builtin_amdgcn_mfma_f32_16x16x32_bf16(a, b, acc[nt], 0, 0, 0);
    }
  }
  {
    float g1c[8], s1c[8];
#pragma unroll
    for (int nt = 0; nt < 8; ++nt) { g1c[nt] = gu1[nt * 16 + lr]; s1c[nt] = su1[nt * 16 + lr]; }
#pragma unroll
    for (int r = 0; r < 4; ++r) {
      float s = 0.f, q = 0.f;
#pragma unroll
      for (int nt = 0; nt < 8; ++nt) { const float v = acc[nt][r]; s += v; q += v * v; }
#pragma unroll
      for (int m = 1; m < 16; m <<= 1) { s += __shfl_xor(s, m); q += __shfl_xor(q, m); }
      const float mu = s * 0.0078125f;
      const float rstd = rsqrtf(q * 0.0078125f - mu * mu + 1e-5f);
      const int row = lg * 4 + r;
#pragma unroll
      for (int nt = 0; nt < 8; ++nt) {
        float v = (acc[nt][r] - mu) * rstd * g1c[nt] + s1c[nt];
        v = silu_f(v);
        const int col = nt * 16 + lr;
        *(__bf16*)(T1 + ((row * 256 + col * 2) ^ ((row & 7) << 4))) = (__bf16)v;
      }
    }
  }
  f32x4 acc2[8];
#pragma unroll
  for (int nt = 0; nt < 8; ++nt) {
    const float bb = bu2[nt * 16 + lr];
#pragma unroll
    for (int r = 0; r < 4; ++r) acc2[nt][r] = bb;
  }
#pragma unroll
  for (int kt = 0; kt < 4; ++kt) {
    const bf16x8 a = *(const bf16x8*)(T1 + ((lr * 256 + kt * 64 + lg * 16) ^ ((lr & 7) << 4)));
#pragma unroll
    for (int nt = 0; nt < 8; ++nt) {
      const bf16x8 b = *(const bf16x8*)(w2p + ((size_t)((kt * 8 + nt) * 64 + l)) * 8);
      acc2[nt] = __builtin_amdgcn_mfma_f32_16x16x32_bf16(a, b, acc2[nt], 0, 0, 0);
    }
  }
  {
    float g2c[8], s2c[8];
#pragma unroll
    for (int nt = 0; nt < 8; ++nt) { g2c[nt] = gu2[nt * 16 + lr]; s2c[nt] = su2[nt * 16 + lr]; }
#pragma unroll
    for (int r = 0; r < 4; ++r) {
      float s = 0.f, q = 0.f;
#pragma unroll
      for (int nt = 0; nt < 8; ++nt) { const float v = acc2[nt][r]; s += v; q += v * v; }
#pragma unroll
      for (int m = 1; m < 16; m <<= 1) { s += __shfl_xor(s, m); q += __shfl_xor(q, m); }
      const float mu = s * 0.0078125f;
      const float rstd = rsqrtf(q * 0.0078125f - mu * mu + 1e-5f);
      const int row = lg * 4 + r;
      const int nn = n0 + row;
      if (nn < NN) {
#pragma unroll
        for (int nt = 0; nt < 8; ++nt) {
          const int col = nt * 16 + lr;
          float v = (acc2[nt][r] - mu) * rstd * g2c[nt] + s2c[nt];
          v = silu_f(v);
          if (mode & 1) v += h0[(size_t)nn * 128 + col];
          if (mode & 2) {
            h[(size_t)nn * 128 + col] = v;          // final: pool input
          } else {
            hbf[(size_t)nn * 128 + col] = (__bf16)v;
            if (mode & 1) h0[(size_t)nn * 128 + col] = v;
          }
        }
      }
    }
  }
}

// ---------------------------------------------------------------------------
__global__ void pool_kernel(const float* __restrict__ h, const int* __restrict__ bid,
                            float* __restrict__ pooled) {
  const int d = threadIdx.x;
  const int n0 = blockIdx.x * 32;
  const int nend = (n0 + 32 < NN) ? (n0 + 32) : NN;
  float acc = 0.f;
  int cur = bid[n0];
  for (int n = n0; n < nend; ++n) {
    const int b = bid[n];
    if (b != cur) { atomicAdd(&pooled[cur * 128 + d], acc); acc = 0.f; cur = b; }
    acc += h[(size_t)n * 128 + d];
  }
  atomicAdd(&pooled[cur * 128 + d], acc);
}

__global__ void head_kernel(const float* __restrict__ pooled,
                            const float* __restrict__ W1, const float* __restrict__ b1,
                            const float* __restrict__ W2, const float* __restrict__ b2,
                            float* __restrict__ out) {
  __shared__ float buf[2];
  const int b = blockIdx.x, t = threadIdx.x;
  float s = b1[t];
  for (int k = 0; k < 128; ++k) s += pooled[b * 128 + k] * W1[k * 128 + t];
  s = fmaxf(s, 0.f) * W2[t];
#pragma unroll
  for (int m = 32; m >= 1; m >>= 1) s += __shfl_down(s, m);
  if ((t & 63) == 0) buf[t >> 6] = s;
  __syncthreads();
  if (t == 0) out[b] = buf[0] + buf[1] + b2[0];
}

// ---------------------------------------------------------------------------
extern "C" void kernel_launch(void* const* d_in, const int* in_sizes, int n_in,
                              void* d_out, int out_size, void* d_ws, size_t ws_size,
                              hipStream_t stream) {
  const float* x   = (const float*)d_in[0];
  const float* pos = (const float*)d_in[1];
  const int* eis[4] = {(const int*)d_in[2], (const int*)d_in[3],
                       (const int*)d_in[4], (const int*)d_in[5]};
  const int* bid = (const int*)d_in[6];
  const float* embW = (const float*)d_in[7];
  const float* embB = (const float*)d_in[8];
  const float* Wm1 = (const float*)d_in[9];
  const float* bm1 = (const float*)d_in[10];
  const float* gm1 = (const float*)d_in[11];
  const float* sm1 = (const float*)d_in[12];
  const float* Wm2 = (const float*)d_in[13];
  const float* bm2 = (const float*)d_in[14];
  const float* gm2 = (const float*)d_in[15];
  const float* sm2 = (const float*)d_in[16];
  const float* Wu1 = (const float*)d_in[17];
  const float* bu1 = (const float*)d_in[18];
  const float* gu1 = (const float*)d_in[19];
  const float* su1 = (const float*)d_in[20];
  const float* Wu2 = (const float*)d_in[21];
  const float* bu2 = (const float*)d_in[22];
  const float* gu2 = (const float*)d_in[23];
  const float* su2 = (const float*)d_in[24];
  const float* pW1 = (const float*)d_in[25];
  const float* pb1 = (const float*)d_in[26];
  const float* pW2 = (const float*)d_in[27];
  const float* pb2 = (const float*)d_in[28];
  float* out = (float*)d_out;

  char* wp = (char*)d_ws;
  float* h = (float*)wp;      wp += (size_t)NN * 128 * 4;
  float* h0 = (float*)wp;     wp += (size_t)NN * 128 * 4;
  float* pooled = (float*)wp; wp += 16 * 128 * 4;
  __bf16* aggb = (__bf16*)wp; wp += (size_t)NN * 128 * 2;
  __bf16* hbf = (__bf16*)wp;  wp += (size_t)NN * 128 * 2;
  __bf16* pq = (__bf16*)wp;   wp += (size_t)NN * 256 * 2;
  __bf16* msg = (__bf16*)wp;  wp += (size_t)NE * 128 * 2;
  __bf16* pqw = (__bf16*)wp;  wp += (size_t)NL * 32768 * 2;
  __bf16* w2p = (__bf16*)wp;  wp += (size_t)NL * 16384 * 2;
  __bf16* wu1p = (__bf16*)wp; wp += (size_t)NL * 32768 * 2;
  __bf16* wu2p = (__bf16*)wp; wp += (size_t)NL * 16384 * 2;
  int* deg = (int*)wp;        wp += (size_t)4 * NN * 4;
  int* cursor = (int*)wp;     wp += (size_t)4 * NN * 4;
  int* rowstart = (int*)wp;   wp += (size_t)4 * NN * 4;
  int* esrc = (int*)wp;       wp += (size_t)4 * NE * 4;
  int* edst = (int*)wp;       wp += (size_t)4 * NE * 4;

  static int lds_attr_set = 0;
  if (!lds_attr_set) {
    hipFuncSetAttribute((const void*)edge_msg_kernel,
                        hipFuncAttributeMaxDynamicSharedMemorySize, 49152);
    lds_attr_set = 1;
  }

  pack_w1pq<<<320, 256, 0, stream>>>(Wm1, pqw);
  pack_weights<<<160, 256, 0, stream>>>(Wm2, w2p, 128, 128 * 128, NL * 4 * 8 * 64);
  pack_weights<<<320, 256, 0, stream>>>(Wu1, wu1p, 256, 256 * 128, NL * 8 * 8 * 64);
  pack_weights<<<160, 256, 0, stream>>>(Wu2, wu2p, 128, 128 * 128, NL * 4 * 8 * 64);

  hipMemsetAsync(deg, 0, (size_t)8 * NN * 4, stream);
  embed_kernel<<<(NN * 128) / 256, 256, 0, stream>>>(x, embW, embB, h0, hbf);
  for (int r = 0; r < 4; ++r)
    hist_kernel<<<NE / 256, 256, 0, stream>>>(eis[r], deg + (size_t)r * NN);
  scan_kernel<<<4, 1024, 0, stream>>>(deg, rowstart);
  for (int r = 0; r < 4; ++r)
    fill_kernel<<<NE / 256, 256, 0, stream>>>(eis[r], rowstart + (size_t)r * NN,
                                              cursor + (size_t)r * NN,
                                              esrc + (size_t)r * NE, edst + (size_t)r * NE);

  for (int layer = 0; layer < 5; ++layer) {
    for (int r = 0; r < 4; ++r) {
      const int i = layer * 4 + r;
      const int mode = (r == 3) ? ((layer == 4) ? 3 : 1) : 0;
      pq_kernel<<<625, 256, 0, stream>>>(hbf, pqw + (size_t)i * 32768, pq);
      edge_msg_kernel<<<NE / 128, 512, 49152, stream>>>(
          pq, pos, esrc + (size_t)r * NE, edst + (size_t)r * NE, msg,
          w2p + (size_t)i * 16384,
          Wm1 + (size_t)i * 257 * 128 + 256 * 128,
          bm1 + i * 128, gm1 + i * 128, sm1 + i * 128,
          bm2 + i * 128, gm2 + i * 128, sm2 + i * 128);
      gather_kernel<<<(NN * 64) / 256, 256, 0, stream>>>(
          msg, rowstart + (size_t)r * NN, deg + (size_t)r * NN, aggb);
      update_kernel<<<(NN + 63) / 64, 256, 0, stream>>>(
          h, aggb, hbf, h0, mode,
          wu1p + (size_t)i * 32768, wu2p + (size_t)i * 16384,
          bu1 + i * 128, gu1 + i * 128, su1 + i * 128,
          bu2 + i * 128, gu2 + i * 128, su2 + i * 128);
    }
  }

  hipMemsetAsync(pooled, 0, 16 * 128 * 4, stream);
  pool_kernel<<<(NN + 31) / 32, 128, 0, stream>>>(h, bid, pooled);
  head_kernel<<<16, 128, 0, stream>>>(pooled, pW1, pb1, pW2, pb2, out);
}